// Round 2
// baseline (540.237 us; speedup 1.0000x reference)
//
#include <hip/hip_runtime.h>
#include <hip/hip_bf16.h>
#include <math.h>

// Problem constants (fixed by setup_inputs: B=4, L=2048)
#define BB      4
#define LL      2048
#define KNB     30
#define NRES    (BB*LL)          // 8192
#define NEDGE   (NRES*KNB)       // 245760
#define EDGE_IN 416              // 16 pos + 25*16 RBF = 13 * 32
#define KT      13               // K-tiles of 32
#define KTA     7                // pass-A k-tiles (features 0..223)
#define ME      32               // edges per block in edge kernel
#define AST2    232              // A-tile row stride in fp16 for 7-tile buffer (464 B, 16B-aligned)

typedef __attribute__((ext_vector_type(8))) _Float16 half8;
typedef __attribute__((ext_vector_type(4))) float floatx4;

__device__ __constant__ int d_PA[25] = {0,1,2,3,4,0,0,0,0,1,1,1,4,4,3,1,2,3,4,2,3,4,2,3,2};
__device__ __constant__ int d_PB[25] = {0,1,2,3,4,1,2,3,4,2,3,4,2,3,2,0,0,0,0,1,1,1,4,4,3};

__device__ __forceinline__ unsigned short f2h_bits(float x) {
    _Float16 h = (_Float16)x;
    union { _Float16 h; unsigned short u; } v; v.h = h;
    return v.u;
}
__device__ __forceinline__ unsigned pack2h(float a, float b) {
    return (unsigned)f2h_bits(a) | ((unsigned)f2h_bits(b) << 16);
}

// ---------------------------------------------------------------------------
// Kernel 1: per-residue atom construction.  atoms[r][5][3] = [Ca,N,C,O,Cb]
// ---------------------------------------------------------------------------
__global__ __launch_bounds__(256) void atoms_kernel(const float* __restrict__ X,
                                                    float* __restrict__ atoms) {
    int r = blockIdx.x * blockDim.x + threadIdx.x;
    if (r >= NRES) return;
    const float* xr = X + (size_t)r * 12;
    float Nx = xr[0],  Ny = xr[1],  Nz = xr[2];
    float Ax = xr[3],  Ay = xr[4],  Az = xr[5];   // Ca
    float Cx = xr[6],  Cy = xr[7],  Cz = xr[8];
    float Ox = xr[9],  Oy = xr[10], Oz = xr[11];
    float bx = Ax - Nx, by = Ay - Ny, bz = Az - Nz;
    float cx = Cx - Ax, cy = Cy - Ay, cz = Cz - Az;
    float ax = by * cz - bz * cy;
    float ay = bz * cx - bx * cz;
    float az = bx * cy - by * cx;
    float Cbx = -0.58273431f * ax + 0.56802827f * bx - 0.54067466f * cx + Ax;
    float Cby = -0.58273431f * ay + 0.56802827f * by - 0.54067466f * cy + Ay;
    float Cbz = -0.58273431f * az + 0.56802827f * bz - 0.54067466f * cz + Az;
    float* o = atoms + (size_t)r * 15;
    o[0]  = Ax;  o[1]  = Ay;  o[2]  = Az;
    o[3]  = Nx;  o[4]  = Ny;  o[5]  = Nz;
    o[6]  = Cx;  o[7]  = Cy;  o[8]  = Cz;
    o[9]  = Ox;  o[10] = Oy;  o[11] = Oz;
    o[12] = Cbx; o[13] = Cby; o[14] = Cbz;
}

// ---------------------------------------------------------------------------
// Kernel 2: top-K neighbor selection — ONE WAVE PER RESIDUE, REGISTER-RESIDENT.
// 32 f32 values per lane (index j = i*64+lane is implicit in the register
// slot, never stored).  Per round: 5-level pairwise tree-min carrying a 5-bit
// slot index (depth 5, all compile-time register indices), 6-step 32-bit
// (value, j) butterfly, then winner invalidation via readfirstlane + scalar
// compares (no dynamic register indexing, no pop-shift, no 64-bit keys).
// Distances bit-exact vs the fp32 numpy pipeline (contract off, same exprs).
// ---------------------------------------------------------------------------
__global__ __launch_bounds__(256) void topk_kernel(const float* __restrict__ X,
                                                   const float* __restrict__ mask,
                                                   int* __restrict__ E_idx) {
#pragma clang fp contract(off)
    int t    = threadIdx.x;
    int wid  = t >> 6;
    int lane = t & 63;
    int bi   = blockIdx.x * 4 + wid;      // residue
    int b    = bi >> 11;
    int j0   = b << 11;

    const float* cai = X + ((size_t)bi * 4 + 1) * 3;
    float cx = cai[0], cy = cai[1], cz = cai[2];
    float mi = mask[bi];

    float a[32];
    float lmax = 0.0f;
#pragma unroll
    for (int i = 0; i < 32; i++) {
        int j = i * 64 + lane;
        const float* cj = X + (((size_t)(j0 + j)) * 4 + 1) * 3;
        float dx = cx - cj[0], dy = cy - cj[1], dz = cz - cj[2];
        float ssq = ((dx * dx + dy * dy) + dz * dz) + 1e-6f;
        float m2  = mask[j0 + j] * mi;
        float Dj  = m2 * sqrtf(ssq);
        a[i] = Dj;
        lmax = fmaxf(lmax, Dj);
    }
    for (int off = 32; off; off >>= 1) lmax = fmaxf(lmax, __shfl_xor(lmax, off));
    // mask adjustment (exact no-op when mask==1)
#pragma unroll
    for (int i = 0; i < 32; i++) {
        float m2 = mask[j0 + i * 64 + lane] * mi;
        a[i] = a[i] + (1.0f - m2) * lmax;
    }

    int* outp = E_idx + (size_t)bi * KNB;
#pragma unroll 1
    for (int r = 0; r < KNB; r++) {
        // --- tree min over the 32 registers; ties keep the LOWER slot ---
        float v[16]; int ix[16];
#pragma unroll
        for (int i = 0; i < 16; i++) {
            bool sw = a[2 * i + 1] < a[2 * i];
            v[i]  = sw ? a[2 * i + 1] : a[2 * i];
            ix[i] = sw ? 2 * i + 1 : 2 * i;
        }
#pragma unroll
        for (int n = 8; n >= 1; n >>= 1) {
#pragma unroll
            for (int i = 0; i < n; i++) {
                bool sw = v[2 * i + 1] < v[2 * i];
                v[i]  = sw ? v[2 * i + 1] : v[2 * i];
                ix[i] = sw ? ix[2 * i + 1] : ix[2 * i];
            }
        }
        float bv = v[0];
        int   bj = (ix[0] << 6) | lane;      // global j within the row
        // --- 64-lane butterfly min on (value, j), lexicographic ---
        for (int off = 1; off < 64; off <<= 1) {
            float ov = __shfl_xor(bv, off);
            int   oj = __shfl_xor(bj, off);
            if (ov < bv || (ov == bv && oj < bj)) { bv = ov; bj = oj; }
        }
        if (lane == 0) outp[r] = bj;
        // --- invalidate winner: scalar slot compare + per-lane predicate ---
        int  wi   = __builtin_amdgcn_readfirstlane((unsigned)bj >> 6);
        bool mine = (lane == (bj & 63));
#pragma unroll
        for (int i = 0; i < 32; i++)
            if (i == wi && mine) a[i] = 3.4e38f;
    }
}

// ---------------------------------------------------------------------------
// Kernel 2.5: pre-swizzle W_edge (fp32 [416][128]) into SPLIT fp16 B-fragment
// order: Wh = fp16(W), Wl = fp16(W - Wh).  Layout [kk][nt][lane] of half8:
// element holds W[k = kk*32 + (lane>>4)*8 + j][n = nt*16 + (lane&15)].
// ---------------------------------------------------------------------------
__global__ __launch_bounds__(256) void wprep_kernel(const float* __restrict__ W_edge,
                                                    half8* __restrict__ Wfh,
                                                    half8* __restrict__ Wfl) {
    int t = blockIdx.x * blockDim.x + threadIdx.x;
    if (t >= KT * 8 * 64) return;
    int kk   = t >> 9;
    int rem  = t & 511;
    int nt   = rem >> 6;
    int lane = rem & 63;
    int n  = nt * 16 + (lane & 15);
    int kb = kk * 32 + (lane >> 4) * 8;
    half8 vh, vl;
#pragma unroll
    for (int j = 0; j < 8; j++) {
        float w = W_edge[(size_t)(kb + j) * 128 + n];
        _Float16 wh = (_Float16)w;
        vh[j] = wh;
        vl[j] = (_Float16)(w - (float)wh);
    }
    Wfh[t] = vh;
    Wfl[t] = vl;
}

// ---------------------------------------------------------------------------
// Kernel 3: edge featurization (SPLIT fp16 A-tile) + 3-term MFMA GEMM + LN.
// Block = 32 edges.  Wave w: edge strip (w&1)*16, feature half (w>>1)*64.
// E = Ah*Wh + Al*Wh + Ah*Wl  (fp32 accum; dropped Al*Wl ~ 2^-22).
// K-dimension time-split over a SINGLE half-size A buffer (fill 0..6 ->
// GEMM -> refill 7..12 -> GEMM); acc carried in registers => bit-identical.
// B fragments ping-pong through a compile-time-indexed B[2][4] register
// double-buffer (fully unrolled K loops) => zero register copies per k-tile
// (was 64 v_movs/kk under the rotate scheme).
// ---------------------------------------------------------------------------
__global__ __launch_bounds__(256) void edge_kernel(const float* __restrict__ atoms,
                                                   const int* __restrict__ E_idx,
                                                   const int* __restrict__ resi,
                                                   const float* __restrict__ W_pos,
                                                   const float* __restrict__ b_pos,
                                                   const half8* __restrict__ Wfh,
                                                   const half8* __restrict__ Wfl,
                                                   const float* __restrict__ gamma,
                                                   const float* __restrict__ beta,
                                                   float* __restrict__ out) {
    __shared__ _Float16 Ah[ME * AST2];             // 14848 B
    __shared__ _Float16 Al[ME * AST2];             // 14848 B
    __shared__ float Dl[ME][26];                   //  3328 B
    __shared__ float redS[2][ME];                  //   256 B
    __shared__ int   s_gi[ME], s_gj[ME], s_d[ME];  //   384 B

    int t  = threadIdx.x;
    int e0 = blockIdx.x * ME;

    if (t < ME) {
        int e  = e0 + t;
        int gi = e / KNB;
        int k  = e - gi * KNB;
        int b  = gi >> 11;
        int j  = E_idx[(size_t)gi * KNB + k];
        s_gi[t] = gi;
        s_gj[t] = (b << 11) + j;
        int off = resi[gi] - resi[(b << 11) + j];
        int d = off + 32;
        s_d[t] = d < 0 ? 0 : (d > 64 ? 64 : d);
    }
    __syncthreads();

    for (int idx = t; idx < ME * 25; idx += 256) {
        int e = idx / 25, p = idx - e * 25;
        const float* Ar = atoms + (size_t)s_gi[e] * 15 + d_PA[p] * 3;
        const float* Br = atoms + (size_t)s_gj[e] * 15 + d_PB[p] * 3;
        float dx = Ar[0] - Br[0];
        float dy = Ar[1] - Br[1];
        float dz = Ar[2] - Br[2];
        Dl[e][p] = sqrtf(dx * dx + dy * dy + dz * dz + 1e-6f);
    }
    __syncthreads();

    // --- fill pass A: features 0..223 (pos-emb + RBF pairs p=0..12) ---
    {
        int e  = t >> 3;           // 0..31
        int j8 = t & 7;
        const float* dle = Dl[e];
        _Float16* ah = &Ah[e * AST2];
        _Float16* al = &Al[e * AST2];
        if (j8 < 4) {              // pos-emb features c = j8*4 .. +3
            int c = j8 * 4;
            int dpos = s_d[e];
            const float* wp = W_pos + dpos * 16 + c;
            float v[4];
#pragma unroll
            for (int q = 0; q < 4; q++) v[q] = wp[q] + b_pos[c + q];
            float h0 = (float)(_Float16)v[0], h1 = (float)(_Float16)v[1];
            float h2 = (float)(_Float16)v[2], h3 = (float)(_Float16)v[3];
            *(unsigned*)&ah[c + 0] = pack2h(v[0], v[1]);
            *(unsigned*)&ah[c + 2] = pack2h(v[2], v[3]);
            *(unsigned*)&al[c + 0] = pack2h(v[0] - h0, v[1] - h1);
            *(unsigned*)&al[c + 2] = pack2h(v[2] - h2, v[3] - h3);
        }
        // RBF features: c2 = 2*(j8 + 8i), i = 0..12 — covers even 0..206
#pragma unroll
        for (int i = 0; i < 13; i++) {
            int c2 = 2 * (j8 + 8 * i);
            int p  = c2 >> 4;
            int r  = c2 & 15;
            float D = dle[p];
            float mu0 = 2.0f + (float)r * (20.0f / 15.0f);
            float mu1 = 2.0f + (float)(r + 1) * (20.0f / 15.0f);
            float t0 = (D - mu0) * 0.8f;
            float t1 = (D - mu1) * 0.8f;
            float g0 = expf(-t0 * t0);
            float g1 = expf(-t1 * t1);
            float h0 = (float)(_Float16)g0, h1 = (float)(_Float16)g1;
            *(unsigned*)&ah[16 + c2] = pack2h(g0, g1);
            *(unsigned*)&al[16 + c2] = pack2h(g0 - h0, g1 - h1);
        }
    }
    __syncthreads();

    // --- MFMA GEMM: 32x416 x 416x128 -> fp32, split precision, K time-split ---
    int lane  = t & 63;
    int w     = t >> 6;
    int strip = (w & 1) * 16;      // edge strip base
    int h     = w >> 1;            // feature half (0: n 0..63, 1: n 64..127)
    int m     = lane & 15;
    int quad  = lane >> 4;
    const _Float16* pah = &Ah[(strip + m) * AST2 + quad * 8];
    const _Float16* pal = &Al[(strip + m) * AST2 + quad * 8];

    floatx4 acc[4];
#pragma unroll
    for (int c = 0; c < 4; c++) acc[c] = (floatx4){0.f, 0.f, 0.f, 0.f};

    half8 Bh[2][4], Bl[2][4];
#pragma unroll
    for (int c = 0; c < 4; c++) {
        int idx = (h * 4 + c) * 64 + lane;
        Bh[0][c] = Wfh[idx];
        Bl[0][c] = Wfl[idx];
    }

    // pass A: k-tiles 0..6 (prefetch of kk+1 always valid: kk+1 <= 7 <= 12)
#pragma unroll
    for (int kk = 0; kk < KTA; kk++) {
        const int cur = kk & 1, nxt = cur ^ 1;
        half8 a_hi = *(const half8*)(pah + kk * 32);
        half8 a_lo = *(const half8*)(pal + kk * 32);
#pragma unroll
        for (int c = 0; c < 4; c++) {
            int idx = ((kk + 1) * 8 + h * 4 + c) * 64 + lane;
            Bh[nxt][c] = Wfh[idx];
            Bl[nxt][c] = Wfl[idx];
        }
#pragma unroll
        for (int c = 0; c < 4; c++) {
            acc[c] = __builtin_amdgcn_mfma_f32_16x16x32_f16(a_hi, Bh[cur][c], acc[c], 0, 0, 0);
            acc[c] = __builtin_amdgcn_mfma_f32_16x16x32_f16(a_lo, Bh[cur][c], acc[c], 0, 0, 0);
            acc[c] = __builtin_amdgcn_mfma_f32_16x16x32_f16(a_hi, Bl[cur][c], acc[c], 0, 0, 0);
        }
    }

    __syncthreads();   // all waves done reading buffer before overwrite

    // --- fill pass B: features 224..415 (RBF pairs p=13..24) into same buffer ---
    {
        int e  = t >> 3;
        int j8 = t & 7;
        const float* dle = Dl[e];
        _Float16* ah = &Ah[e * AST2];
        _Float16* al = &Al[e * AST2];
        // c2 = 2*(j8 + 8i), i = 13..24 — covers even 208..398; col = c2-208
#pragma unroll
        for (int i = 13; i < 25; i++) {
            int c2 = 2 * (j8 + 8 * i);
            int p  = c2 >> 4;
            int r  = c2 & 15;
            float D = dle[p];
            float mu0 = 2.0f + (float)r * (20.0f / 15.0f);
            float mu1 = 2.0f + (float)(r + 1) * (20.0f / 15.0f);
            float t0 = (D - mu0) * 0.8f;
            float t1 = (D - mu1) * 0.8f;
            float g0 = expf(-t0 * t0);
            float g1 = expf(-t1 * t1);
            float h0 = (float)(_Float16)g0, h1 = (float)(_Float16)g1;
            int col = c2 - 208;
            *(unsigned*)&ah[col] = pack2h(g0, g1);
            *(unsigned*)&al[col] = pack2h(g0 - h0, g1 - h1);
        }
    }
    __syncthreads();

    // pass B: k-tiles 7..12 (B[7&1=1] holds k-tile 7 from pass-A's last prefetch)
#pragma unroll
    for (int kk = KTA; kk < KT; kk++) {
        const int cur = kk & 1, nxt = cur ^ 1;
        half8 a_hi = *(const half8*)(pah + (kk - KTA) * 32);
        half8 a_lo = *(const half8*)(pal + (kk - KTA) * 32);
        if (kk < KT - 1) {
#pragma unroll
            for (int c = 0; c < 4; c++) {
                int idx = ((kk + 1) * 8 + h * 4 + c) * 64 + lane;
                Bh[nxt][c] = Wfh[idx];
                Bl[nxt][c] = Wfl[idx];
            }
        }
#pragma unroll
        for (int c = 0; c < 4; c++) {
            acc[c] = __builtin_amdgcn_mfma_f32_16x16x32_f16(a_hi, Bh[cur][c], acc[c], 0, 0, 0);
            acc[c] = __builtin_amdgcn_mfma_f32_16x16x32_f16(a_lo, Bh[cur][c], acc[c], 0, 0, 0);
            acc[c] = __builtin_amdgcn_mfma_f32_16x16x32_f16(a_hi, Bl[cur][c], acc[c], 0, 0, 0);
        }
    }

    // --- LayerNorm epilogue: per edge, features split across wave pairs ---
    // D[row = quad*4 + r][col = m]; edge_local = strip + quad*4 + r.
    int elb = strip + quad * 4;
    float sarr[4];
#pragma unroll
    for (int r = 0; r < 4; r++) {
        float s = acc[0][r] + acc[1][r] + acc[2][r] + acc[3][r];
        for (int msk = 1; msk <= 8; msk <<= 1) s += __shfl_xor(s, msk);
        sarr[r] = s;                       // this wave's 64-feature partial
    }
    if (m == 0) {
#pragma unroll
        for (int r = 0; r < 4; r++) redS[h][elb + r] = sarr[r];
    }
    __syncthreads();
    float mu[4];
#pragma unroll
    for (int r = 0; r < 4; r++) mu[r] = (redS[0][elb + r] + redS[1][elb + r]) * (1.0f / 128.0f);
    __syncthreads();
    float dvv[4][4];
#pragma unroll
    for (int r = 0; r < 4; r++) {
        float v = 0.f;
#pragma unroll
        for (int c = 0; c < 4; c++) { dvv[c][r] = acc[c][r] - mu[r]; v += dvv[c][r] * dvv[c][r]; }
        for (int msk = 1; msk <= 8; msk <<= 1) v += __shfl_xor(v, msk);
        if (m == 0) redS[h][elb + r] = v;
    }
    __syncthreads();
#pragma unroll
    for (int r = 0; r < 4; r++) {
        float var  = (redS[0][elb + r] + redS[1][elb + r]) * (1.0f / 128.0f);
        float rstd = rsqrtf(var + 1e-5f);
        int e = e0 + elb + r;
        float* orow = out + (size_t)e * 128;
#pragma unroll
        for (int c = 0; c < 4; c++) {
            int n = (h * 4 + c) * 16 + m;
            orow[n] = dvv[c][r] * rstd * gamma[n] + beta[n];
        }
    }
}

// ---------------------------------------------------------------------------
extern "C" void kernel_launch(void* const* d_in, const int* in_sizes, int n_in,
                              void* d_out, int out_size, void* d_ws, size_t ws_size,
                              hipStream_t stream) {
    const float* X      = (const float*)d_in[0];
    const float* mask   = (const float*)d_in[1];
    const int*   resi   = (const int*)  d_in[2];
    const float* W_pos  = (const float*)d_in[3];
    const float* b_pos  = (const float*)d_in[4];
    const float* W_edge = (const float*)d_in[5];
    const float* gamma  = (const float*)d_in[6];
    const float* beta   = (const float*)d_in[7];
    float* out = (float*)d_out;

    float* atoms = (float*)d_ws;                                     // 491520 B
    int*   E_idx = (int*)((char*)d_ws + (size_t)NRES * 15 * 4);      // 983040 B
    half8* Wfh   = (half8*)((char*)d_ws + 1474560);                  // 106496 B
    half8* Wfl   = (half8*)((char*)d_ws + 1581056);                  // 106496 B

    atoms_kernel<<<(NRES + 255) / 256, 256, 0, stream>>>(X, atoms);
    wprep_kernel<<<(KT * 8 * 64 + 255) / 256, 256, 0, stream>>>(W_edge, Wfh, Wfl);
    topk_kernel<<<NRES / 4, 256, 0, stream>>>(X, mask, E_idx);
    edge_kernel<<<NEDGE / ME, 256, 0, stream>>>(atoms, E_idx, resi,
                                                W_pos, b_pos, Wfh, Wfl, gamma, beta, out);
}

// Round 3
// 338.612 us; speedup vs baseline: 1.5954x; 1.5954x over previous
//
#include <hip/hip_runtime.h>
#include <hip/hip_bf16.h>
#include <math.h>

// Problem constants (fixed by setup_inputs: B=4, L=2048)
#define BB      4
#define LL      2048
#define KNB     30
#define NRES    (BB*LL)          // 8192
#define NEDGE   (NRES*KNB)       // 245760
#define EDGE_IN 416              // 16 pos + 25*16 RBF = 13 * 32
#define KT      13               // K-tiles of 32
#define KTA     7                // pass-A k-tiles (features 0..223)
#define ME      32               // edges per block in edge kernel
#define AST2    232              // A-tile row stride in fp16 for 7-tile buffer (464 B, 16B-aligned)
#define FINF    3.4e38f

typedef __attribute__((ext_vector_type(8))) _Float16 half8;
typedef __attribute__((ext_vector_type(4))) float floatx4;

__device__ __constant__ int d_PA[25] = {0,1,2,3,4,0,0,0,0,1,1,1,4,4,3,1,2,3,4,2,3,4,2,3,2};
__device__ __constant__ int d_PB[25] = {0,1,2,3,4,1,2,3,4,2,3,4,2,3,2,0,0,0,0,1,1,1,4,4,3};

__device__ __forceinline__ unsigned short f2h_bits(float x) {
    _Float16 h = (_Float16)x;
    union { _Float16 h; unsigned short u; } v; v.h = h;
    return v.u;
}
__device__ __forceinline__ unsigned pack2h(float a, float b) {
    return (unsigned)f2h_bits(a) | ((unsigned)f2h_bits(b) << 16);
}

// ---------------------------------------------------------------------------
// Kernel 1: per-residue atom construction.  atoms[r][5][3] = [Ca,N,C,O,Cb]
// ---------------------------------------------------------------------------
__global__ __launch_bounds__(256) void atoms_kernel(const float* __restrict__ X,
                                                    float* __restrict__ atoms) {
    int r = blockIdx.x * blockDim.x + threadIdx.x;
    if (r >= NRES) return;
    const float* xr = X + (size_t)r * 12;
    float Nx = xr[0],  Ny = xr[1],  Nz = xr[2];
    float Ax = xr[3],  Ay = xr[4],  Az = xr[5];   // Ca
    float Cx = xr[6],  Cy = xr[7],  Cz = xr[8];
    float Ox = xr[9],  Oy = xr[10], Oz = xr[11];
    float bx = Ax - Nx, by = Ay - Ny, bz = Az - Nz;
    float cx = Cx - Ax, cy = Cy - Ay, cz = Cz - Az;
    float ax = by * cz - bz * cy;
    float ay = bz * cx - bx * cz;
    float az = bx * cy - by * cx;
    float Cbx = -0.58273431f * ax + 0.56802827f * bx - 0.54067466f * cx + Ax;
    float Cby = -0.58273431f * ay + 0.56802827f * by - 0.54067466f * cy + Ay;
    float Cbz = -0.58273431f * az + 0.56802827f * bz - 0.54067466f * cz + Az;
    float* o = atoms + (size_t)r * 15;
    o[0]  = Ax;  o[1]  = Ay;  o[2]  = Az;
    o[3]  = Nx;  o[4]  = Ny;  o[5]  = Nz;
    o[6]  = Cx;  o[7]  = Cy;  o[8]  = Cz;
    o[9]  = Ox;  o[10] = Oy;  o[11] = Oz;
    o[12] = Cbx; o[13] = Cby; o[14] = Cbz;
}

// ---------------------------------------------------------------------------
// Kernel 2: top-K — ONE WAVE PER RESIDUE, cached-head tournament.
// Each lane: 4 smallest of its 32 values in sorted registers (value + slot),
// full adjusted values in LDS.  Per round: 6-step lexicographic butterfly
// over the 64 lane-heads, winner pops its head (masked cndmasks) and INF-marks
// its LDS slot.  A lane that exhausts its 4-cache (wins a 5th time; ~0.9% of
// waves) refills via an exec-masked LDS rescan — rare but fully correct.
// Distances bit-exact vs the fp32 numpy pipeline (contract off, same exprs);
// selection is exact lexicographic (value, j) => identical E_idx.
// ---------------------------------------------------------------------------
__global__ __launch_bounds__(256) void topk_kernel(const float* __restrict__ X,
                                                   const float* __restrict__ mask,
                                                   int* __restrict__ E_idx) {
#pragma clang fp contract(off)
    __shared__ float Dv[4][LL];

    int t    = threadIdx.x;
    int wid  = t >> 6;
    int lane = t & 63;
    int bi   = blockIdx.x * 4 + wid;      // residue
    int b    = bi >> 11;
    int j0   = b << 11;

    const float* cai = X + ((size_t)bi * 4 + 1) * 3;
    float cx = cai[0], cy = cai[1], cz = cai[2];
    float mi = mask[bi];
    float* dv = Dv[wid];

    float aa[32];
    float lmax = 0.0f;
#pragma unroll
    for (int i = 0; i < 32; i++) {
        int j = i * 64 + lane;
        const float* cj = X + (((size_t)(j0 + j)) * 4 + 1) * 3;
        float dx = cx - cj[0], dy = cy - cj[1], dz = cz - cj[2];
        float ssq = ((dx * dx + dy * dy) + dz * dz) + 1e-6f;
        float m2  = mask[j0 + j] * mi;
        float Dj  = m2 * sqrtf(ssq);
        aa[i] = Dj;
        lmax = fmaxf(lmax, Dj);
    }
    for (int off = 32; off; off >>= 1) lmax = fmaxf(lmax, __shfl_xor(lmax, off));

    // adjust (exact no-op when mask==1), store to LDS, build sorted-4 cache
    float l0 = FINF, l1 = FINF, l2 = FINF, l3 = FINF;
    int   i0 = 0,    i1 = 0,    i2 = 0,    i3 = 0;     // slot; global j = (slot<<6)|lane
#pragma unroll
    for (int i = 0; i < 32; i++) {
        float m2 = mask[j0 + i * 64 + lane] * mi;
        float v  = aa[i] + (1.0f - m2) * lmax;
        dv[i * 64 + lane] = v;
        bool c0 = v < l0, c1 = v < l1, c2 = v < l2, c3 = v < l3;
        l3 = c2 ? l2 : (c3 ? v : l3);  i3 = c2 ? i2 : (c3 ? i : i3);
        l2 = c1 ? l1 : (c2 ? v : l2);  i2 = c1 ? i1 : (c2 ? i : i2);
        l1 = c0 ? l0 : (c1 ? v : l1);  i1 = c0 ? i0 : (c1 ? i : i1);
        l0 = c0 ? v  : l0;             i0 = c0 ? i  : i0;
    }

    int* outp = E_idx + (size_t)bi * KNB;
#pragma unroll 1
    for (int r = 0; r < KNB; r++) {
        float bv = l0;
        int   bj = (i0 << 6) | lane;
        for (int off = 1; off < 64; off <<= 1) {
            float ov = __shfl_xor(bv, off);
            int   oj = __shfl_xor(bj, off);
            if (ov < bv || (ov == bv && oj < bj)) { bv = ov; bj = oj; }
        }
        if (lane == 0) outp[r] = bj;
        bool mine = ((bj & 63) == lane);
        if (mine) {
            dv[bj] = FINF;                       // mark consumed (own slot)
            l0 = l1; i0 = i1;
            l1 = l2; i1 = i2;
            l2 = l3; i2 = i3;
            l3 = FINF;
        }
        bool need = mine && (l0 == FINF) && (r < KNB - 1);
        if (need) {                              // rare: lane won a 5th time
            l0 = FINF; l1 = FINF; l2 = FINF; l3 = FINF;
            i0 = 0; i1 = 0; i2 = 0; i3 = 0;
#pragma unroll
            for (int i = 0; i < 32; i++) {
                float v = dv[i * 64 + lane];     // consumed entries are INF
                bool c0 = v < l0, c1 = v < l1, c2 = v < l2, c3 = v < l3;
                l3 = c2 ? l2 : (c3 ? v : l3);  i3 = c2 ? i2 : (c3 ? i : i3);
                l2 = c1 ? l1 : (c2 ? v : l2);  i2 = c1 ? i1 : (c2 ? i : i2);
                l1 = c0 ? l0 : (c1 ? v : l1);  i1 = c0 ? i0 : (c1 ? i : i1);
                l0 = c0 ? v  : l0;             i0 = c0 ? i  : i0;
            }
        }
    }
}

// ---------------------------------------------------------------------------
// Kernel 2.5: pre-swizzle W_edge (fp32 [416][128]) into SPLIT fp16 B-fragment
// order: Wh = fp16(W), Wl = fp16(W - Wh).  Layout [kk][nt][lane] of half8:
// element holds W[k = kk*32 + (lane>>4)*8 + j][n = nt*16 + (lane&15)].
// ---------------------------------------------------------------------------
__global__ __launch_bounds__(256) void wprep_kernel(const float* __restrict__ W_edge,
                                                    half8* __restrict__ Wfh,
                                                    half8* __restrict__ Wfl) {
    int t = blockIdx.x * blockDim.x + threadIdx.x;
    if (t >= KT * 8 * 64) return;
    int kk   = t >> 9;
    int rem  = t & 511;
    int nt   = rem >> 6;
    int lane = rem & 63;
    int n  = nt * 16 + (lane & 15);
    int kb = kk * 32 + (lane >> 4) * 8;
    half8 vh, vl;
#pragma unroll
    for (int j = 0; j < 8; j++) {
        float w = W_edge[(size_t)(kb + j) * 128 + n];
        _Float16 wh = (_Float16)w;
        vh[j] = wh;
        vl[j] = (_Float16)(w - (float)wh);
    }
    Wfh[t] = vh;
    Wfl[t] = vl;
}

// ---------------------------------------------------------------------------
// Kernel 3: edge featurization (SPLIT fp16 A-tile) + 3-term MFMA GEMM + LN.
// REVERTED to the round-1 form (166 us measured): K time-split over a single
// half-size A buffer, `#pragma unroll 1` K-loops with register rotation.
// (The fully-unrolled B[2][4] ping-pong variant regressed to ~235 us.)
// ---------------------------------------------------------------------------
__global__ __launch_bounds__(256) void edge_kernel(const float* __restrict__ atoms,
                                                   const int* __restrict__ E_idx,
                                                   const int* __restrict__ resi,
                                                   const float* __restrict__ W_pos,
                                                   const float* __restrict__ b_pos,
                                                   const half8* __restrict__ Wfh,
                                                   const half8* __restrict__ Wfl,
                                                   const float* __restrict__ gamma,
                                                   const float* __restrict__ beta,
                                                   float* __restrict__ out) {
    __shared__ _Float16 Ah[ME * AST2];             // 14848 B
    __shared__ _Float16 Al[ME * AST2];             // 14848 B
    __shared__ float Dl[ME][26];                   //  3328 B
    __shared__ float redS[2][ME];                  //   256 B
    __shared__ int   s_gi[ME], s_gj[ME], s_d[ME];  //   384 B

    int t  = threadIdx.x;
    int e0 = blockIdx.x * ME;

    if (t < ME) {
        int e  = e0 + t;
        int gi = e / KNB;
        int k  = e - gi * KNB;
        int b  = gi >> 11;
        int j  = E_idx[(size_t)gi * KNB + k];
        s_gi[t] = gi;
        s_gj[t] = (b << 11) + j;
        int off = resi[gi] - resi[(b << 11) + j];
        int d = off + 32;
        s_d[t] = d < 0 ? 0 : (d > 64 ? 64 : d);
    }
    __syncthreads();

    for (int idx = t; idx < ME * 25; idx += 256) {
        int e = idx / 25, p = idx - e * 25;
        const float* Ar = atoms + (size_t)s_gi[e] * 15 + d_PA[p] * 3;
        const float* Br = atoms + (size_t)s_gj[e] * 15 + d_PB[p] * 3;
        float dx = Ar[0] - Br[0];
        float dy = Ar[1] - Br[1];
        float dz = Ar[2] - Br[2];
        Dl[e][p] = sqrtf(dx * dx + dy * dy + dz * dz + 1e-6f);
    }
    __syncthreads();

    // --- fill pass A: features 0..223 (pos-emb + RBF pairs p=0..12) ---
    {
        int e  = t >> 3;           // 0..31
        int j8 = t & 7;
        const float* dle = Dl[e];
        _Float16* ah = &Ah[e * AST2];
        _Float16* al = &Al[e * AST2];
        if (j8 < 4) {              // pos-emb features c = j8*4 .. +3
            int c = j8 * 4;
            int dpos = s_d[e];
            const float* wp = W_pos + dpos * 16 + c;
            float v[4];
#pragma unroll
            for (int q = 0; q < 4; q++) v[q] = wp[q] + b_pos[c + q];
            float h0 = (float)(_Float16)v[0], h1 = (float)(_Float16)v[1];
            float h2 = (float)(_Float16)v[2], h3 = (float)(_Float16)v[3];
            *(unsigned*)&ah[c + 0] = pack2h(v[0], v[1]);
            *(unsigned*)&ah[c + 2] = pack2h(v[2], v[3]);
            *(unsigned*)&al[c + 0] = pack2h(v[0] - h0, v[1] - h1);
            *(unsigned*)&al[c + 2] = pack2h(v[2] - h2, v[3] - h3);
        }
        // RBF features: c2 = 2*(j8 + 8i), i = 0..12 — covers even 0..206
#pragma unroll
        for (int i = 0; i < 13; i++) {
            int c2 = 2 * (j8 + 8 * i);
            int p  = c2 >> 4;
            int r  = c2 & 15;
            float D = dle[p];
            float mu0 = 2.0f + (float)r * (20.0f / 15.0f);
            float mu1 = 2.0f + (float)(r + 1) * (20.0f / 15.0f);
            float t0 = (D - mu0) * 0.8f;
            float t1 = (D - mu1) * 0.8f;
            float g0 = expf(-t0 * t0);
            float g1 = expf(-t1 * t1);
            float h0 = (float)(_Float16)g0, h1 = (float)(_Float16)g1;
            *(unsigned*)&ah[16 + c2] = pack2h(g0, g1);
            *(unsigned*)&al[16 + c2] = pack2h(g0 - h0, g1 - h1);
        }
    }
    __syncthreads();

    // --- MFMA GEMM: 32x416 x 416x128 -> fp32, split precision, K time-split ---
    int lane  = t & 63;
    int w     = t >> 6;
    int strip = (w & 1) * 16;      // edge strip base
    int h     = w >> 1;            // feature half (0: n 0..63, 1: n 64..127)
    int m     = lane & 15;
    int quad  = lane >> 4;
    const _Float16* pah = &Ah[(strip + m) * AST2 + quad * 8];
    const _Float16* pal = &Al[(strip + m) * AST2 + quad * 8];

    floatx4 acc[4];
#pragma unroll
    for (int c = 0; c < 4; c++) acc[c] = (floatx4){0.f, 0.f, 0.f, 0.f};

    half8 bh[4], bl[4], bnh[4], bnl[4];
#pragma unroll
    for (int c = 0; c < 4; c++) {
        int idx = (h * 4 + c) * 64 + lane;
        bh[c] = Wfh[idx];
        bl[c] = Wfl[idx];
    }

    // pass A: k-tiles 0..6 (prefetch of kk+1 always valid: kk+1 <= 7)
#pragma unroll 1
    for (int kk = 0; kk < KTA; kk++) {
        half8 a_hi = *(const half8*)(pah + kk * 32);
        half8 a_lo = *(const half8*)(pal + kk * 32);
#pragma unroll
        for (int c = 0; c < 4; c++) {
            int idx = ((kk + 1) * 8 + h * 4 + c) * 64 + lane;
            bnh[c] = Wfh[idx];
            bnl[c] = Wfl[idx];
        }
#pragma unroll
        for (int c = 0; c < 4; c++) {
            acc[c] = __builtin_amdgcn_mfma_f32_16x16x32_f16(a_hi, bh[c], acc[c], 0, 0, 0);
            acc[c] = __builtin_amdgcn_mfma_f32_16x16x32_f16(a_lo, bh[c], acc[c], 0, 0, 0);
            acc[c] = __builtin_amdgcn_mfma_f32_16x16x32_f16(a_hi, bl[c], acc[c], 0, 0, 0);
        }
#pragma unroll
        for (int c = 0; c < 4; c++) { bh[c] = bnh[c]; bl[c] = bnl[c]; }
    }

    __syncthreads();   // all waves done reading buffer before overwrite

    // --- fill pass B: features 224..415 (RBF pairs p=13..24) into same buffer ---
    {
        int e  = t >> 3;
        int j8 = t & 7;
        const float* dle = Dl[e];
        _Float16* ah = &Ah[e * AST2];
        _Float16* al = &Al[e * AST2];
        // c2 = 2*(j8 + 8i), i = 13..24 — covers even 208..398; col = c2-208
#pragma unroll
        for (int i = 13; i < 25; i++) {
            int c2 = 2 * (j8 + 8 * i);
            int p  = c2 >> 4;
            int r  = c2 & 15;
            float D = dle[p];
            float mu0 = 2.0f + (float)r * (20.0f / 15.0f);
            float mu1 = 2.0f + (float)(r + 1) * (20.0f / 15.0f);
            float t0 = (D - mu0) * 0.8f;
            float t1 = (D - mu1) * 0.8f;
            float g0 = expf(-t0 * t0);
            float g1 = expf(-t1 * t1);
            float h0 = (float)(_Float16)g0, h1 = (float)(_Float16)g1;
            int col = c2 - 208;
            *(unsigned*)&ah[col] = pack2h(g0, g1);
            *(unsigned*)&al[col] = pack2h(g0 - h0, g1 - h1);
        }
    }
    __syncthreads();

    // pass B: k-tiles 7..12 (bh currently holds B(7) from pass-A pipeline)
#pragma unroll 1
    for (int kk = KTA; kk < KT; kk++) {
        half8 a_hi = *(const half8*)(pah + (kk - KTA) * 32);
        half8 a_lo = *(const half8*)(pal + (kk - KTA) * 32);
        if (kk < KT - 1) {
#pragma unroll
            for (int c = 0; c < 4; c++) {
                int idx = ((kk + 1) * 8 + h * 4 + c) * 64 + lane;
                bnh[c] = Wfh[idx];
                bnl[c] = Wfl[idx];
            }
        }
#pragma unroll
        for (int c = 0; c < 4; c++) {
            acc[c] = __builtin_amdgcn_mfma_f32_16x16x32_f16(a_hi, bh[c], acc[c], 0, 0, 0);
            acc[c] = __builtin_amdgcn_mfma_f32_16x16x32_f16(a_lo, bh[c], acc[c], 0, 0, 0);
            acc[c] = __builtin_amdgcn_mfma_f32_16x16x32_f16(a_hi, bl[c], acc[c], 0, 0, 0);
        }
#pragma unroll
        for (int c = 0; c < 4; c++) { bh[c] = bnh[c]; bl[c] = bnl[c]; }
    }

    // --- LayerNorm epilogue: per edge, features split across wave pairs ---
    // D[row = quad*4 + r][col = m]; edge_local = strip + quad*4 + r.
    int elb = strip + quad * 4;
    float sarr[4];
#pragma unroll
    for (int r = 0; r < 4; r++) {
        float s = acc[0][r] + acc[1][r] + acc[2][r] + acc[3][r];
        for (int msk = 1; msk <= 8; msk <<= 1) s += __shfl_xor(s, msk);
        sarr[r] = s;                       // this wave's 64-feature partial
    }
    if (m == 0) {
#pragma unroll
        for (int r = 0; r < 4; r++) redS[h][elb + r] = sarr[r];
    }
    __syncthreads();
    float mu[4];
#pragma unroll
    for (int r = 0; r < 4; r++) mu[r] = (redS[0][elb + r] + redS[1][elb + r]) * (1.0f / 128.0f);
    __syncthreads();
    float dvv[4][4];
#pragma unroll
    for (int r = 0; r < 4; r++) {
        float v = 0.f;
#pragma unroll
        for (int c = 0; c < 4; c++) { dvv[c][r] = acc[c][r] - mu[r]; v += dvv[c][r] * dvv[c][r]; }
        for (int msk = 1; msk <= 8; msk <<= 1) v += __shfl_xor(v, msk);
        if (m == 0) redS[h][elb + r] = v;
    }
    __syncthreads();
#pragma unroll
    for (int r = 0; r < 4; r++) {
        float var  = (redS[0][elb + r] + redS[1][elb + r]) * (1.0f / 128.0f);
        float rstd = rsqrtf(var + 1e-5f);
        int e = e0 + elb + r;
        float* orow = out + (size_t)e * 128;
#pragma unroll
        for (int c = 0; c < 4; c++) {
            int n = (h * 4 + c) * 16 + m;
            orow[n] = dvv[c][r] * rstd * gamma[n] + beta[n];
        }
    }
}

// ---------------------------------------------------------------------------
extern "C" void kernel_launch(void* const* d_in, const int* in_sizes, int n_in,
                              void* d_out, int out_size, void* d_ws, size_t ws_size,
                              hipStream_t stream) {
    const float* X      = (const float*)d_in[0];
    const float* mask   = (const float*)d_in[1];
    const int*   resi   = (const int*)  d_in[2];
    const float* W_pos  = (const float*)d_in[3];
    const float* b_pos  = (const float*)d_in[4];
    const float* W_edge = (const float*)d_in[5];
    const float* gamma  = (const float*)d_in[6];
    const float* beta   = (const float*)d_in[7];
    float* out = (float*)d_out;

    float* atoms = (float*)d_ws;                                     // 491520 B
    int*   E_idx = (int*)((char*)d_ws + (size_t)NRES * 15 * 4);      // 983040 B
    half8* Wfh   = (half8*)((char*)d_ws + 1474560);                  // 106496 B
    half8* Wfl   = (half8*)((char*)d_ws + 1581056);                  // 106496 B

    atoms_kernel<<<(NRES + 255) / 256, 256, 0, stream>>>(X, atoms);
    wprep_kernel<<<(KT * 8 * 64 + 255) / 256, 256, 0, stream>>>(W_edge, Wfh, Wfl);
    topk_kernel<<<NRES / 4, 256, 0, stream>>>(X, mask, E_idx);
    edge_kernel<<<NEDGE / ME, 256, 0, stream>>>(atoms, E_idx, resi,
                                                W_pos, b_pos, Wfh, Wfl, gamma, beta, out);
}

// Round 4
// 321.343 us; speedup vs baseline: 1.6812x; 1.0537x over previous
//
#include <hip/hip_runtime.h>
#include <hip/hip_bf16.h>
#include <math.h>

// Problem constants (fixed by setup_inputs: B=4, L=2048)
#define BB      4
#define LL      2048
#define KNB     30
#define NRES    (BB*LL)          // 8192
#define NEDGE   (NRES*KNB)       // 245760
#define EDGE_IN 416              // 16 pos + 25*16 RBF = 13 * 32
#define KT      13               // K-tiles of 32
#define KTA     7                // pass-A k-tiles (features 0..223)
#define ME      32               // edges per block in edge kernel
#define AST2    232              // A-tile row stride in fp16 for 7-tile buffer (464 B, 16B-aligned)
#define FINF    3.4e38f
#define LOG2E   1.44269504088896340736f

typedef __attribute__((ext_vector_type(8))) _Float16 half8;
typedef __attribute__((ext_vector_type(4))) float floatx4;

__device__ __constant__ int d_PA[25] = {0,1,2,3,4,0,0,0,0,1,1,1,4,4,3,1,2,3,4,2,3,4,2,3,2};
__device__ __constant__ int d_PB[25] = {0,1,2,3,4,1,2,3,4,2,3,4,2,3,2,0,0,0,0,1,1,1,4,4,3};

__device__ __forceinline__ unsigned short f2h_bits(float x) {
    _Float16 h = (_Float16)x;
    union { _Float16 h; unsigned short u; } v; v.h = h;
    return v.u;
}
__device__ __forceinline__ unsigned pack2h(float a, float b) {
    return (unsigned)f2h_bits(a) | ((unsigned)f2h_bits(b) << 16);
}

// ---------------------------------------------------------------------------
// Kernel 1: per-residue atom construction.  atoms[r][5][3] = [Ca,N,C,O,Cb].
// ALSO emits an SoA transpose of Ca (caTx/caTy/caTz) so topk's distance loop
// can read coordinates coalesced (the AoS layout forced stride-48B gathers
// that serialized ~48 cache-line segments per wave64 load in the TA pipe).
// ---------------------------------------------------------------------------
__global__ __launch_bounds__(256) void atoms_kernel(const float* __restrict__ X,
                                                    float* __restrict__ atoms,
                                                    float* __restrict__ caTx,
                                                    float* __restrict__ caTy,
                                                    float* __restrict__ caTz) {
    int r = blockIdx.x * blockDim.x + threadIdx.x;
    if (r >= NRES) return;
    const float* xr = X + (size_t)r * 12;
    float Nx = xr[0],  Ny = xr[1],  Nz = xr[2];
    float Ax = xr[3],  Ay = xr[4],  Az = xr[5];   // Ca
    float Cx = xr[6],  Cy = xr[7],  Cz = xr[8];
    float Ox = xr[9],  Oy = xr[10], Oz = xr[11];
    float bx = Ax - Nx, by = Ay - Ny, bz = Az - Nz;
    float cx = Cx - Ax, cy = Cy - Ay, cz = Cz - Az;
    float ax = by * cz - bz * cy;
    float ay = bz * cx - bx * cz;
    float az = bx * cy - by * cx;
    float Cbx = -0.58273431f * ax + 0.56802827f * bx - 0.54067466f * cx + Ax;
    float Cby = -0.58273431f * ay + 0.56802827f * by - 0.54067466f * cy + Ay;
    float Cbz = -0.58273431f * az + 0.56802827f * bz - 0.54067466f * cz + Az;
    float* o = atoms + (size_t)r * 15;
    o[0]  = Ax;  o[1]  = Ay;  o[2]  = Az;
    o[3]  = Nx;  o[4]  = Ny;  o[5]  = Nz;
    o[6]  = Cx;  o[7]  = Cy;  o[8]  = Cz;
    o[9]  = Ox;  o[10] = Oy;  o[11] = Oz;
    o[12] = Cbx; o[13] = Cby; o[14] = Cbz;
    caTx[r] = Ax; caTy[r] = Ay; caTz[r] = Az;     // exact copies of X values
}

// ---------------------------------------------------------------------------
// Kernel 2: top-K — ONE WAVE PER RESIDUE, cached-head tournament, with
// COALESCED coordinate loads from the SoA transpose (caTx/y/z).
// Each lane: 4 smallest of its 32 values in sorted registers (value + slot),
// full adjusted values in LDS.  Per round: 6-step lexicographic butterfly
// over the 64 lane-heads, winner pops its head and INF-marks its LDS slot.
// A lane that exhausts its 4-cache (rare) refills via an exec-masked rescan.
// Distances bit-exact vs the fp32 numpy pipeline (contract off, same exprs);
// selection is exact lexicographic (value, j) => identical E_idx.
// ---------------------------------------------------------------------------
__global__ __launch_bounds__(256) void topk_kernel(const float* __restrict__ caTx,
                                                   const float* __restrict__ caTy,
                                                   const float* __restrict__ caTz,
                                                   const float* __restrict__ mask,
                                                   int* __restrict__ E_idx) {
#pragma clang fp contract(off)
    __shared__ float Dv[4][LL];

    int t    = threadIdx.x;
    int wid  = t >> 6;
    int lane = t & 63;
    int bi   = blockIdx.x * 4 + wid;      // residue
    int b    = bi >> 11;
    int j0   = b << 11;

    float cx = caTx[bi], cy = caTy[bi], cz = caTz[bi];
    float mi = mask[bi];
    float* dv = Dv[wid];

    float aa[32];
    float lmax = 0.0f;
#pragma unroll
    for (int i = 0; i < 32; i++) {
        int j = j0 + i * 64 + lane;
        float dx = cx - caTx[j], dy = cy - caTy[j], dz = cz - caTz[j];
        float ssq = ((dx * dx + dy * dy) + dz * dz) + 1e-6f;
        float m2  = mask[j] * mi;
        float Dj  = m2 * sqrtf(ssq);
        aa[i] = Dj;
        lmax = fmaxf(lmax, Dj);
    }
    for (int off = 32; off; off >>= 1) lmax = fmaxf(lmax, __shfl_xor(lmax, off));

    // adjust (exact no-op when mask==1), store to LDS, build sorted-4 cache
    float l0 = FINF, l1 = FINF, l2 = FINF, l3 = FINF;
    int   i0 = 0,    i1 = 0,    i2 = 0,    i3 = 0;     // slot; global j = (slot<<6)|lane
#pragma unroll
    for (int i = 0; i < 32; i++) {
        float m2 = mask[j0 + i * 64 + lane] * mi;
        float v  = aa[i] + (1.0f - m2) * lmax;
        dv[i * 64 + lane] = v;
        bool c0 = v < l0, c1 = v < l1, c2 = v < l2, c3 = v < l3;
        l3 = c2 ? l2 : (c3 ? v : l3);  i3 = c2 ? i2 : (c3 ? i : i3);
        l2 = c1 ? l1 : (c2 ? v : l2);  i2 = c1 ? i1 : (c2 ? i : i2);
        l1 = c0 ? l0 : (c1 ? v : l1);  i1 = c0 ? i0 : (c1 ? i : i1);
        l0 = c0 ? v  : l0;             i0 = c0 ? i  : i0;
    }

    int* outp = E_idx + (size_t)bi * KNB;
#pragma unroll 1
    for (int r = 0; r < KNB; r++) {
        float bv = l0;
        int   bj = (i0 << 6) | lane;
        for (int off = 1; off < 64; off <<= 1) {
            float ov = __shfl_xor(bv, off);
            int   oj = __shfl_xor(bj, off);
            if (ov < bv || (ov == bv && oj < bj)) { bv = ov; bj = oj; }
        }
        if (lane == 0) outp[r] = bj;
        bool mine = ((bj & 63) == lane);
        if (mine) {
            dv[bj] = FINF;                       // mark consumed (own slot)
            l0 = l1; i0 = i1;
            l1 = l2; i1 = i2;
            l2 = l3; i2 = i3;
            l3 = FINF;
        }
        bool need = mine && (l0 == FINF) && (r < KNB - 1);
        if (need) {                              // rare: lane won a 5th time
            l0 = FINF; l1 = FINF; l2 = FINF; l3 = FINF;
            i0 = 0; i1 = 0; i2 = 0; i3 = 0;
#pragma unroll
            for (int i = 0; i < 32; i++) {
                float v = dv[i * 64 + lane];     // consumed entries are INF
                bool c0 = v < l0, c1 = v < l1, c2 = v < l2, c3 = v < l3;
                l3 = c2 ? l2 : (c3 ? v : l3);  i3 = c2 ? i2 : (c3 ? i : i3);
                l2 = c1 ? l1 : (c2 ? v : l2);  i2 = c1 ? i1 : (c2 ? i : i2);
                l1 = c0 ? l0 : (c1 ? v : l1);  i1 = c0 ? i0 : (c1 ? i : i1);
                l0 = c0 ? v  : l0;             i0 = c0 ? i  : i0;
            }
        }
    }
}

// ---------------------------------------------------------------------------
// Kernel 2.5: pre-swizzle W_edge (fp32 [416][128]) into SPLIT fp16 B-fragment
// order: Wh = fp16(W), Wl = fp16(W - Wh).  Layout [kk][nt][lane] of half8:
// element holds W[k = kk*32 + (lane>>4)*8 + j][n = nt*16 + (lane&15)].
// ---------------------------------------------------------------------------
__global__ __launch_bounds__(256) void wprep_kernel(const float* __restrict__ W_edge,
                                                    half8* __restrict__ Wfh,
                                                    half8* __restrict__ Wfl) {
    int t = blockIdx.x * blockDim.x + threadIdx.x;
    if (t >= KT * 8 * 64) return;
    int kk   = t >> 9;
    int rem  = t & 511;
    int nt   = rem >> 6;
    int lane = rem & 63;
    int n  = nt * 16 + (lane & 15);
    int kb = kk * 32 + (lane >> 4) * 8;
    half8 vh, vl;
#pragma unroll
    for (int j = 0; j < 8; j++) {
        float w = W_edge[(size_t)(kb + j) * 128 + n];
        _Float16 wh = (_Float16)w;
        vh[j] = wh;
        vl[j] = (_Float16)(w - (float)wh);
    }
    Wfh[t] = vh;
    Wfl[t] = vl;
}

// ---------------------------------------------------------------------------
// Kernel 3: edge featurization (SPLIT fp16 A-tile) + 3-term MFMA GEMM + LN.
// Round-1 structure (166 us measured; VGPR 52 proves the compiler already
// folds the B prefetch into the consumed regs — no rotation movs exist).
// Only change: expf -> hw exp2 (v_exp_f32), <=1 ulp, absorbed by the split
// residual => output unchanged at tolerance.
// ---------------------------------------------------------------------------
__global__ __launch_bounds__(256) void edge_kernel(const float* __restrict__ atoms,
                                                   const int* __restrict__ E_idx,
                                                   const int* __restrict__ resi,
                                                   const float* __restrict__ W_pos,
                                                   const float* __restrict__ b_pos,
                                                   const half8* __restrict__ Wfh,
                                                   const half8* __restrict__ Wfl,
                                                   const float* __restrict__ gamma,
                                                   const float* __restrict__ beta,
                                                   float* __restrict__ out) {
    __shared__ _Float16 Ah[ME * AST2];             // 14848 B
    __shared__ _Float16 Al[ME * AST2];             // 14848 B
    __shared__ float Dl[ME][26];                   //  3328 B
    __shared__ float redS[2][ME];                  //   256 B
    __shared__ int   s_gi[ME], s_gj[ME], s_d[ME];  //   384 B

    int t  = threadIdx.x;
    int e0 = blockIdx.x * ME;

    if (t < ME) {
        int e  = e0 + t;
        int gi = e / KNB;
        int k  = e - gi * KNB;
        int b  = gi >> 11;
        int j  = E_idx[(size_t)gi * KNB + k];
        s_gi[t] = gi;
        s_gj[t] = (b << 11) + j;
        int off = resi[gi] - resi[(b << 11) + j];
        int d = off + 32;
        s_d[t] = d < 0 ? 0 : (d > 64 ? 64 : d);
    }
    __syncthreads();

    for (int idx = t; idx < ME * 25; idx += 256) {
        int e = idx / 25, p = idx - e * 25;
        const float* Ar = atoms + (size_t)s_gi[e] * 15 + d_PA[p] * 3;
        const float* Br = atoms + (size_t)s_gj[e] * 15 + d_PB[p] * 3;
        float dx = Ar[0] - Br[0];
        float dy = Ar[1] - Br[1];
        float dz = Ar[2] - Br[2];
        Dl[e][p] = sqrtf(dx * dx + dy * dy + dz * dz + 1e-6f);
    }
    __syncthreads();

    // --- fill pass A: features 0..223 (pos-emb + RBF pairs p=0..12) ---
    {
        int e  = t >> 3;           // 0..31
        int j8 = t & 7;
        const float* dle = Dl[e];
        _Float16* ah = &Ah[e * AST2];
        _Float16* al = &Al[e * AST2];
        if (j8 < 4) {              // pos-emb features c = j8*4 .. +3
            int c = j8 * 4;
            int dpos = s_d[e];
            const float* wp = W_pos + dpos * 16 + c;
            float v[4];
#pragma unroll
            for (int q = 0; q < 4; q++) v[q] = wp[q] + b_pos[c + q];
            float h0 = (float)(_Float16)v[0], h1 = (float)(_Float16)v[1];
            float h2 = (float)(_Float16)v[2], h3 = (float)(_Float16)v[3];
            *(unsigned*)&ah[c + 0] = pack2h(v[0], v[1]);
            *(unsigned*)&ah[c + 2] = pack2h(v[2], v[3]);
            *(unsigned*)&al[c + 0] = pack2h(v[0] - h0, v[1] - h1);
            *(unsigned*)&al[c + 2] = pack2h(v[2] - h2, v[3] - h3);
        }
        // RBF features: c2 = 2*(j8 + 8i), i = 0..12 — covers even 0..206
#pragma unroll
        for (int i = 0; i < 13; i++) {
            int c2 = 2 * (j8 + 8 * i);
            int p  = c2 >> 4;
            int r  = c2 & 15;
            float D = dle[p];
            float mu0 = 2.0f + (float)r * (20.0f / 15.0f);
            float mu1 = 2.0f + (float)(r + 1) * (20.0f / 15.0f);
            float t0 = (D - mu0) * 0.8f;
            float t1 = (D - mu1) * 0.8f;
            float g0 = __builtin_amdgcn_exp2f(-(t0 * t0) * LOG2E);
            float g1 = __builtin_amdgcn_exp2f(-(t1 * t1) * LOG2E);
            float h0 = (float)(_Float16)g0, h1 = (float)(_Float16)g1;
            *(unsigned*)&ah[16 + c2] = pack2h(g0, g1);
            *(unsigned*)&al[16 + c2] = pack2h(g0 - h0, g1 - h1);
        }
    }
    __syncthreads();

    // --- MFMA GEMM: 32x416 x 416x128 -> fp32, split precision, K time-split ---
    int lane  = t & 63;
    int w     = t >> 6;
    int strip = (w & 1) * 16;      // edge strip base
    int h     = w >> 1;            // feature half (0: n 0..63, 1: n 64..127)
    int m     = lane & 15;
    int quad  = lane >> 4;
    const _Float16* pah = &Ah[(strip + m) * AST2 + quad * 8];
    const _Float16* pal = &Al[(strip + m) * AST2 + quad * 8];

    floatx4 acc[4];
#pragma unroll
    for (int c = 0; c < 4; c++) acc[c] = (floatx4){0.f, 0.f, 0.f, 0.f};

    half8 bh[4], bl[4], bnh[4], bnl[4];
#pragma unroll
    for (int c = 0; c < 4; c++) {
        int idx = (h * 4 + c) * 64 + lane;
        bh[c] = Wfh[idx];
        bl[c] = Wfl[idx];
    }

    // pass A: k-tiles 0..6 (prefetch of kk+1 always valid: kk+1 <= 7)
#pragma unroll 1
    for (int kk = 0; kk < KTA; kk++) {
        half8 a_hi = *(const half8*)(pah + kk * 32);
        half8 a_lo = *(const half8*)(pal + kk * 32);
#pragma unroll
        for (int c = 0; c < 4; c++) {
            int idx = ((kk + 1) * 8 + h * 4 + c) * 64 + lane;
            bnh[c] = Wfh[idx];
            bnl[c] = Wfl[idx];
        }
#pragma unroll
        for (int c = 0; c < 4; c++) {
            acc[c] = __builtin_amdgcn_mfma_f32_16x16x32_f16(a_hi, bh[c], acc[c], 0, 0, 0);
            acc[c] = __builtin_amdgcn_mfma_f32_16x16x32_f16(a_lo, bh[c], acc[c], 0, 0, 0);
            acc[c] = __builtin_amdgcn_mfma_f32_16x16x32_f16(a_hi, bl[c], acc[c], 0, 0, 0);
        }
#pragma unroll
        for (int c = 0; c < 4; c++) { bh[c] = bnh[c]; bl[c] = bnl[c]; }
    }

    __syncthreads();   // all waves done reading buffer before overwrite

    // --- fill pass B: features 224..415 (RBF pairs p=13..24) into same buffer ---
    {
        int e  = t >> 3;
        int j8 = t & 7;
        const float* dle = Dl[e];
        _Float16* ah = &Ah[e * AST2];
        _Float16* al = &Al[e * AST2];
        // c2 = 2*(j8 + 8i), i = 13..24 — covers even 208..398; col = c2-208
#pragma unroll
        for (int i = 13; i < 25; i++) {
            int c2 = 2 * (j8 + 8 * i);
            int p  = c2 >> 4;
            int r  = c2 & 15;
            float D = dle[p];
            float mu0 = 2.0f + (float)r * (20.0f / 15.0f);
            float mu1 = 2.0f + (float)(r + 1) * (20.0f / 15.0f);
            float t0 = (D - mu0) * 0.8f;
            float t1 = (D - mu1) * 0.8f;
            float g0 = __builtin_amdgcn_exp2f(-(t0 * t0) * LOG2E);
            float g1 = __builtin_amdgcn_exp2f(-(t1 * t1) * LOG2E);
            float h0 = (float)(_Float16)g0, h1 = (float)(_Float16)g1;
            int col = c2 - 208;
            *(unsigned*)&ah[col] = pack2h(g0, g1);
            *(unsigned*)&al[col] = pack2h(g0 - h0, g1 - h1);
        }
    }
    __syncthreads();

    // pass B: k-tiles 7..12 (bh currently holds B(7) from pass-A pipeline)
#pragma unroll 1
    for (int kk = KTA; kk < KT; kk++) {
        half8 a_hi = *(const half8*)(pah + (kk - KTA) * 32);
        half8 a_lo = *(const half8*)(pal + (kk - KTA) * 32);
        if (kk < KT - 1) {
#pragma unroll
            for (int c = 0; c < 4; c++) {
                int idx = ((kk + 1) * 8 + h * 4 + c) * 64 + lane;
                bnh[c] = Wfh[idx];
                bnl[c] = Wfl[idx];
            }
        }
#pragma unroll
        for (int c = 0; c < 4; c++) {
            acc[c] = __builtin_amdgcn_mfma_f32_16x16x32_f16(a_hi, bh[c], acc[c], 0, 0, 0);
            acc[c] = __builtin_amdgcn_mfma_f32_16x16x32_f16(a_lo, bh[c], acc[c], 0, 0, 0);
            acc[c] = __builtin_amdgcn_mfma_f32_16x16x32_f16(a_hi, bl[c], acc[c], 0, 0, 0);
        }
#pragma unroll
        for (int c = 0; c < 4; c++) { bh[c] = bnh[c]; bl[c] = bnl[c]; }
    }

    // --- LayerNorm epilogue: per edge, features split across wave pairs ---
    // D[row = quad*4 + r][col = m]; edge_local = strip + quad*4 + r.
    int elb = strip + quad * 4;
    float sarr[4];
#pragma unroll
    for (int r = 0; r < 4; r++) {
        float s = acc[0][r] + acc[1][r] + acc[2][r] + acc[3][r];
        for (int msk = 1; msk <= 8; msk <<= 1) s += __shfl_xor(s, msk);
        sarr[r] = s;                       // this wave's 64-feature partial
    }
    if (m == 0) {
#pragma unroll
        for (int r = 0; r < 4; r++) redS[h][elb + r] = sarr[r];
    }
    __syncthreads();
    float mu[4];
#pragma unroll
    for (int r = 0; r < 4; r++) mu[r] = (redS[0][elb + r] + redS[1][elb + r]) * (1.0f / 128.0f);
    __syncthreads();
    float dvv[4][4];
#pragma unroll
    for (int r = 0; r < 4; r++) {
        float v = 0.f;
#pragma unroll
        for (int c = 0; c < 4; c++) { dvv[c][r] = acc[c][r] - mu[r]; v += dvv[c][r] * dvv[c][r]; }
        for (int msk = 1; msk <= 8; msk <<= 1) v += __shfl_xor(v, msk);
        if (m == 0) redS[h][elb + r] = v;
    }
    __syncthreads();
#pragma unroll
    for (int r = 0; r < 4; r++) {
        float var  = (redS[0][elb + r] + redS[1][elb + r]) * (1.0f / 128.0f);
        float rstd = rsqrtf(var + 1e-5f);
        int e = e0 + elb + r;
        float* orow = out + (size_t)e * 128;
#pragma unroll
        for (int c = 0; c < 4; c++) {
            int n = (h * 4 + c) * 16 + m;
            orow[n] = dvv[c][r] * rstd * gamma[n] + beta[n];
        }
    }
}

// ---------------------------------------------------------------------------
extern "C" void kernel_launch(void* const* d_in, const int* in_sizes, int n_in,
                              void* d_out, int out_size, void* d_ws, size_t ws_size,
                              hipStream_t stream) {
    const float* X      = (const float*)d_in[0];
    const float* mask   = (const float*)d_in[1];
    const int*   resi   = (const int*)  d_in[2];
    const float* W_pos  = (const float*)d_in[3];
    const float* b_pos  = (const float*)d_in[4];
    const float* W_edge = (const float*)d_in[5];
    const float* gamma  = (const float*)d_in[6];
    const float* beta   = (const float*)d_in[7];
    float* out = (float*)d_out;

    float* atoms = (float*)d_ws;                                     // 491520 B
    int*   E_idx = (int*)((char*)d_ws + (size_t)NRES * 15 * 4);      // 983040 B
    half8* Wfh   = (half8*)((char*)d_ws + 1474560);                  // 106496 B
    half8* Wfl   = (half8*)((char*)d_ws + 1581056);                  // 106496 B
    float* caTx  = (float*)((char*)d_ws + 1687552);                  //  32768 B
    float* caTy  = (float*)((char*)d_ws + 1720320);                  //  32768 B
    float* caTz  = (float*)((char*)d_ws + 1753088);                  //  32768 B

    atoms_kernel<<<(NRES + 255) / 256, 256, 0, stream>>>(X, atoms, caTx, caTy, caTz);
    wprep_kernel<<<(KT * 8 * 64 + 255) / 256, 256, 0, stream>>>(W_edge, Wfh, Wfl);
    topk_kernel<<<NRES / 4, 256, 0, stream>>>(caTx, caTy, caTz, mask, E_idx);
    edge_kernel<<<NEDGE / ME, 256, 0, stream>>>(atoms, E_idx, resi,
                                                W_pos, b_pos, Wfh, Wfl, gamma, beta, out);
}

// Round 5
// 320.727 us; speedup vs baseline: 1.6844x; 1.0019x over previous
//
#include <hip/hip_runtime.h>
#include <hip/hip_bf16.h>
#include <math.h>

// Problem constants (fixed by setup_inputs: B=4, L=2048)
#define BB      4
#define LL      2048
#define KNB     30
#define NRES    (BB*LL)          // 8192
#define NEDGE   (NRES*KNB)       // 245760
#define EDGE_IN 416              // 16 pos + 25*16 RBF = 13 * 32
#define KT      13               // K-tiles of 32
#define ME      32               // edges per block in edge kernel
#define AST3    168              // A-tile row stride in fp16 for 5-tile buffer (336 B, 16B-aligned)
#define FINF    3.4e38f
#define LOG2E   1.44269504088896340736f

typedef __attribute__((ext_vector_type(8))) _Float16 half8;
typedef __attribute__((ext_vector_type(4))) float floatx4;

__device__ __constant__ int d_PA[25] = {0,1,2,3,4,0,0,0,0,1,1,1,4,4,3,1,2,3,4,2,3,4,2,3,2};
__device__ __constant__ int d_PB[25] = {0,1,2,3,4,1,2,3,4,2,3,4,2,3,2,0,0,0,0,1,1,1,4,4,3};

__device__ __forceinline__ unsigned short f2h_bits(float x) {
    _Float16 h = (_Float16)x;
    union { _Float16 h; unsigned short u; } v; v.h = h;
    return v.u;
}
__device__ __forceinline__ unsigned pack2h(float a, float b) {
    return (unsigned)f2h_bits(a) | ((unsigned)f2h_bits(b) << 16);
}

// ---------------------------------------------------------------------------
// Kernel 1: per-residue atom construction.  atoms[r][5][3] = [Ca,N,C,O,Cb].
// Also emits the Ca SoA transpose (caTx/y/z) for coalesced topk loads.
// ---------------------------------------------------------------------------
__global__ __launch_bounds__(256) void atoms_kernel(const float* __restrict__ X,
                                                    float* __restrict__ atoms,
                                                    float* __restrict__ caTx,
                                                    float* __restrict__ caTy,
                                                    float* __restrict__ caTz) {
    int r = blockIdx.x * blockDim.x + threadIdx.x;
    if (r >= NRES) return;
    const float* xr = X + (size_t)r * 12;
    float Nx = xr[0],  Ny = xr[1],  Nz = xr[2];
    float Ax = xr[3],  Ay = xr[4],  Az = xr[5];   // Ca
    float Cx = xr[6],  Cy = xr[7],  Cz = xr[8];
    float Ox = xr[9],  Oy = xr[10], Oz = xr[11];
    float bx = Ax - Nx, by = Ay - Ny, bz = Az - Nz;
    float cx = Cx - Ax, cy = Cy - Ay, cz = Cz - Az;
    float ax = by * cz - bz * cy;
    float ay = bz * cx - bx * cz;
    float az = bx * cy - by * cx;
    float Cbx = -0.58273431f * ax + 0.56802827f * bx - 0.54067466f * cx + Ax;
    float Cby = -0.58273431f * ay + 0.56802827f * by - 0.54067466f * cy + Ay;
    float Cbz = -0.58273431f * az + 0.56802827f * bz - 0.54067466f * cz + Az;
    float* o = atoms + (size_t)r * 15;
    o[0]  = Ax;  o[1]  = Ay;  o[2]  = Az;
    o[3]  = Nx;  o[4]  = Ny;  o[5]  = Nz;
    o[6]  = Cx;  o[7]  = Cy;  o[8]  = Cz;
    o[9]  = Ox;  o[10] = Oy;  o[11] = Oz;
    o[12] = Cbx; o[13] = Cby; o[14] = Cbz;
    caTx[r] = Ax; caTy[r] = Ay; caTz[r] = Az;     // exact copies of X values
}

// ---------------------------------------------------------------------------
// Kernel 2: top-K — ONE WAVE PER RESIDUE, cached-head tournament, ZERO LDS.
// All 32 values live in registers (aa[32], compile-time indexed everywhere).
// Consumption tracked by a per-lane 32-bit bitmask instead of an LDS mirror
// (removes 32 KB LDS -> no occupancy cap, and all per-round LDS traffic).
// Per round: 6-step lexicographic butterfly over the 64 lane-heads; winner
// pops its sorted-4 head; a lane that drains its cache (rare) rebuilds it
// from registers, masking consumed slots.  Distances bit-exact vs the fp32
// numpy pipeline (contract off, same exprs); selection exact lex (value, j).
// ---------------------------------------------------------------------------
__global__ __launch_bounds__(256, 6) void topk_kernel(const float* __restrict__ caTx,
                                                      const float* __restrict__ caTy,
                                                      const float* __restrict__ caTz,
                                                      const float* __restrict__ mask,
                                                      int* __restrict__ E_idx) {
#pragma clang fp contract(off)
    int t    = threadIdx.x;
    int wid  = t >> 6;
    int lane = t & 63;
    int bi   = blockIdx.x * 4 + wid;      // residue
    int b    = bi >> 11;
    int j0   = b << 11;

    float cx = caTx[bi], cy = caTy[bi], cz = caTz[bi];
    float mi = mask[bi];

    float aa[32];
    float lmax = 0.0f;
#pragma unroll
    for (int i = 0; i < 32; i++) {
        int j = j0 + i * 64 + lane;
        float dx = cx - caTx[j], dy = cy - caTy[j], dz = cz - caTz[j];
        float ssq = ((dx * dx + dy * dy) + dz * dz) + 1e-6f;
        float m2  = mask[j] * mi;
        float Dj  = m2 * sqrtf(ssq);
        aa[i] = Dj;
        lmax = fmaxf(lmax, Dj);
    }
    for (int off = 32; off; off >>= 1) lmax = fmaxf(lmax, __shfl_xor(lmax, off));

    // adjust in place (exact no-op when mask==1) and build sorted-4 cache
    float l0 = FINF, l1 = FINF, l2 = FINF, l3 = FINF;
    int   i0 = 0,    i1 = 0,    i2 = 0,    i3 = 0;     // slot; global j = (slot<<6)|lane
#pragma unroll
    for (int i = 0; i < 32; i++) {
        float m2 = mask[j0 + i * 64 + lane] * mi;
        float v  = aa[i] + (1.0f - m2) * lmax;
        aa[i] = v;
        bool c0 = v < l0, c1 = v < l1, c2 = v < l2, c3 = v < l3;
        l3 = c2 ? l2 : (c3 ? v : l3);  i3 = c2 ? i2 : (c3 ? i : i3);
        l2 = c1 ? l1 : (c2 ? v : l2);  i2 = c1 ? i1 : (c2 ? i : i2);
        l1 = c0 ? l0 : (c1 ? v : l1);  i1 = c0 ? i0 : (c1 ? i : i1);
        l0 = c0 ? v  : l0;             i0 = c0 ? i  : i0;
    }

    unsigned consumed = 0;
    int* outp = E_idx + (size_t)bi * KNB;
#pragma unroll 1
    for (int r = 0; r < KNB; r++) {
        float bv = l0;
        int   bj = (i0 << 6) | lane;
        for (int off = 1; off < 64; off <<= 1) {
            float ov = __shfl_xor(bv, off);
            int   oj = __shfl_xor(bj, off);
            if (ov < bv || (ov == bv && oj < bj)) { bv = ov; bj = oj; }
        }
        if (lane == 0) outp[r] = bj;
        bool mine = ((bj & 63) == lane);
        if (mine) {
            consumed |= 1u << ((unsigned)bj >> 6);   // mark own slot consumed
            l0 = l1; i0 = i1;
            l1 = l2; i1 = i2;
            l2 = l3; i2 = i3;
            l3 = FINF;
        }
        bool need = mine && (l0 == FINF) && (r < KNB - 1);
        if (need) {                                  // rare: lane won a 5th time
            l0 = FINF; l1 = FINF; l2 = FINF; l3 = FINF;
            i0 = 0; i1 = 0; i2 = 0; i3 = 0;
#pragma unroll
            for (int i = 0; i < 32; i++) {
                float v = (consumed & (1u << i)) ? FINF : aa[i];
                bool c0 = v < l0, c1 = v < l1, c2 = v < l2, c3 = v < l3;
                l3 = c2 ? l2 : (c3 ? v : l3);  i3 = c2 ? i2 : (c3 ? i : i3);
                l2 = c1 ? l1 : (c2 ? v : l2);  i2 = c1 ? i1 : (c2 ? i : i2);
                l1 = c0 ? l0 : (c1 ? v : l1);  i1 = c0 ? i0 : (c1 ? i : i1);
                l0 = c0 ? v  : l0;             i0 = c0 ? i  : i0;
            }
        }
    }
}

// ---------------------------------------------------------------------------
// Kernel 2.5: pre-swizzle W_edge (fp32 [416][128]) into SPLIT fp16 B-fragment
// order: Wh = fp16(W), Wl = fp16(W - Wh).  Layout [kk][nt][lane] of half8:
// element holds W[k = kk*32 + (lane>>4)*8 + j][n = nt*16 + (lane&15)].
// ---------------------------------------------------------------------------
__global__ __launch_bounds__(256) void wprep_kernel(const float* __restrict__ W_edge,
                                                    half8* __restrict__ Wfh,
                                                    half8* __restrict__ Wfl) {
    int t = blockIdx.x * blockDim.x + threadIdx.x;
    if (t >= KT * 8 * 64) return;
    int kk   = t >> 9;
    int rem  = t & 511;
    int nt   = rem >> 6;
    int lane = rem & 63;
    int n  = nt * 16 + (lane & 15);
    int kb = kk * 32 + (lane >> 4) * 8;
    half8 vh, vl;
#pragma unroll
    for (int j = 0; j < 8; j++) {
        float w = W_edge[(size_t)(kb + j) * 128 + n];
        _Float16 wh = (_Float16)w;
        vh[j] = wh;
        vl[j] = (_Float16)(w - (float)wh);
    }
    Wfh[t] = vh;
    Wfl[t] = vl;
}

// ---------------------------------------------------------------------------
// Kernel 3: edge featurization (SPLIT fp16 A-tile) + 3-term MFMA GEMM + LN.
// E = Ah*Wh + Al*Wh + Ah*Wl (fp32 accum).  K now TIME-SPLIT IN THREE passes
// ({5,4,4} k-tiles) over a single 5-tile A buffer: LDS 33.7KB -> 25.5KB
// => 6 blocks/CU (was 4).  kk order and MFMA sequence unchanged =>
// bit-identical output.  expf -> hw exp2 kept from round 4.
// ---------------------------------------------------------------------------
__global__ __launch_bounds__(256) void edge_kernel(const float* __restrict__ atoms,
                                                   const int* __restrict__ E_idx,
                                                   const int* __restrict__ resi,
                                                   const float* __restrict__ W_pos,
                                                   const float* __restrict__ b_pos,
                                                   const half8* __restrict__ Wfh,
                                                   const half8* __restrict__ Wfl,
                                                   const float* __restrict__ gamma,
                                                   const float* __restrict__ beta,
                                                   float* __restrict__ out) {
    __shared__ _Float16 Ah[ME * AST3];             // 10752 B
    __shared__ _Float16 Al[ME * AST3];             // 10752 B
    __shared__ float Dl[ME][26];                   //  3328 B
    __shared__ float redS[2][ME];                  //   256 B
    __shared__ int   s_gi[ME], s_gj[ME], s_d[ME];  //   384 B

    int t  = threadIdx.x;
    int e0 = blockIdx.x * ME;

    if (t < ME) {
        int e  = e0 + t;
        int gi = e / KNB;
        int k  = e - gi * KNB;
        int b  = gi >> 11;
        int j  = E_idx[(size_t)gi * KNB + k];
        s_gi[t] = gi;
        s_gj[t] = (b << 11) + j;
        int off = resi[gi] - resi[(b << 11) + j];
        int d = off + 32;
        s_d[t] = d < 0 ? 0 : (d > 64 ? 64 : d);
    }
    __syncthreads();

    for (int idx = t; idx < ME * 25; idx += 256) {
        int e = idx / 25, p = idx - e * 25;
        const float* Ar = atoms + (size_t)s_gi[e] * 15 + d_PA[p] * 3;
        const float* Br = atoms + (size_t)s_gj[e] * 15 + d_PB[p] * 3;
        float dx = Ar[0] - Br[0];
        float dy = Ar[1] - Br[1];
        float dz = Ar[2] - Br[2];
        Dl[e][p] = sqrtf(dx * dx + dy * dy + dz * dz + 1e-6f);
    }
    __syncthreads();

    int fe  = t >> 3;           // 0..31 (edge for fill)
    int fj8 = t & 7;
    const float* dle = Dl[fe];
    _Float16* fah = &Ah[fe * AST3];
    _Float16* fal = &Al[fe * AST3];

    // --- fill pass 0: features 0..159 (pos-emb + RBF pairs i=0..8) ---
    {
        if (fj8 < 4) {             // pos-emb features c = fj8*4 .. +3
            int c = fj8 * 4;
            int dpos = s_d[fe];
            const float* wp = W_pos + dpos * 16 + c;
            float v[4];
#pragma unroll
            for (int q = 0; q < 4; q++) v[q] = wp[q] + b_pos[c + q];
            float h0 = (float)(_Float16)v[0], h1 = (float)(_Float16)v[1];
            float h2 = (float)(_Float16)v[2], h3 = (float)(_Float16)v[3];
            *(unsigned*)&fah[c + 0] = pack2h(v[0], v[1]);
            *(unsigned*)&fah[c + 2] = pack2h(v[2], v[3]);
            *(unsigned*)&fal[c + 0] = pack2h(v[0] - h0, v[1] - h1);
            *(unsigned*)&fal[c + 2] = pack2h(v[2] - h2, v[3] - h3);
        }
        // RBF pairs: c2 = 2*(fj8 + 8i), i = 0..8 -> buffer col 16+c2 (<=158)
#pragma unroll
        for (int i = 0; i < 9; i++) {
            int c2 = 2 * (fj8 + 8 * i);
            int p  = c2 >> 4;
            int r  = c2 & 15;
            float D = dle[p];
            float mu0 = 2.0f + (float)r * (20.0f / 15.0f);
            float mu1 = 2.0f + (float)(r + 1) * (20.0f / 15.0f);
            float t0 = (D - mu0) * 0.8f;
            float t1 = (D - mu1) * 0.8f;
            float g0 = __builtin_amdgcn_exp2f(-(t0 * t0) * LOG2E);
            float g1 = __builtin_amdgcn_exp2f(-(t1 * t1) * LOG2E);
            float h0 = (float)(_Float16)g0, h1 = (float)(_Float16)g1;
            *(unsigned*)&fah[16 + c2] = pack2h(g0, g1);
            *(unsigned*)&fal[16 + c2] = pack2h(g0 - h0, g1 - h1);
        }
    }
    __syncthreads();

    // --- MFMA GEMM: 32x416 x 416x128 -> fp32, split precision, 3-way K split ---
    int lane  = t & 63;
    int w     = t >> 6;
    int strip = (w & 1) * 16;      // edge strip base
    int h     = w >> 1;            // feature half (0: n 0..63, 1: n 64..127)
    int m     = lane & 15;
    int quad  = lane >> 4;
    const _Float16* pah = &Ah[(strip + m) * AST3 + quad * 8];
    const _Float16* pal = &Al[(strip + m) * AST3 + quad * 8];

    floatx4 acc[4];
#pragma unroll
    for (int c = 0; c < 4; c++) acc[c] = (floatx4){0.f, 0.f, 0.f, 0.f};

    half8 bh[4], bl[4], bnh[4], bnl[4];
#pragma unroll
    for (int c = 0; c < 4; c++) {
        int idx = (h * 4 + c) * 64 + lane;
        bh[c] = Wfh[idx];
        bl[c] = Wfl[idx];
    }

    // pass 0: k-tiles 0..4 (prefetch kk+1 <= 5 always valid)
#pragma unroll 1
    for (int kk = 0; kk < 5; kk++) {
        half8 a_hi = *(const half8*)(pah + kk * 32);
        half8 a_lo = *(const half8*)(pal + kk * 32);
#pragma unroll
        for (int c = 0; c < 4; c++) {
            int idx = ((kk + 1) * 8 + h * 4 + c) * 64 + lane;
            bnh[c] = Wfh[idx];
            bnl[c] = Wfl[idx];
        }
#pragma unroll
        for (int c = 0; c < 4; c++) {
            acc[c] = __builtin_amdgcn_mfma_f32_16x16x32_f16(a_hi, bh[c], acc[c], 0, 0, 0);
            acc[c] = __builtin_amdgcn_mfma_f32_16x16x32_f16(a_lo, bh[c], acc[c], 0, 0, 0);
            acc[c] = __builtin_amdgcn_mfma_f32_16x16x32_f16(a_hi, bl[c], acc[c], 0, 0, 0);
        }
#pragma unroll
        for (int c = 0; c < 4; c++) { bh[c] = bnh[c]; bl[c] = bnl[c]; }
    }

    __syncthreads();   // all waves done reading buffer

    // --- fill pass 1: features 160..287 (RBF pairs i=9..16), col = c2-144 ---
    {
#pragma unroll
        for (int i = 9; i < 17; i++) {
            int c2 = 2 * (fj8 + 8 * i);
            int p  = c2 >> 4;
            int r  = c2 & 15;
            float D = dle[p];
            float mu0 = 2.0f + (float)r * (20.0f / 15.0f);
            float mu1 = 2.0f + (float)(r + 1) * (20.0f / 15.0f);
            float t0 = (D - mu0) * 0.8f;
            float t1 = (D - mu1) * 0.8f;
            float g0 = __builtin_amdgcn_exp2f(-(t0 * t0) * LOG2E);
            float g1 = __builtin_amdgcn_exp2f(-(t1 * t1) * LOG2E);
            float h0 = (float)(_Float16)g0, h1 = (float)(_Float16)g1;
            int col = c2 - 144;
            *(unsigned*)&fah[col] = pack2h(g0, g1);
            *(unsigned*)&fal[col] = pack2h(g0 - h0, g1 - h1);
        }
    }
    __syncthreads();

    // pass 1: k-tiles 5..8 (prefetch kk+1 <= 9 always valid)
#pragma unroll 1
    for (int kk = 5; kk < 9; kk++) {
        half8 a_hi = *(const half8*)(pah + (kk - 5) * 32);
        half8 a_lo = *(const half8*)(pal + (kk - 5) * 32);
#pragma unroll
        for (int c = 0; c < 4; c++) {
            int idx = ((kk + 1) * 8 + h * 4 + c) * 64 + lane;
            bnh[c] = Wfh[idx];
            bnl[c] = Wfl[idx];
        }
#pragma unroll
        for (int c = 0; c < 4; c++) {
            acc[c] = __builtin_amdgcn_mfma_f32_16x16x32_f16(a_hi, bh[c], acc[c], 0, 0, 0);
            acc[c] = __builtin_amdgcn_mfma_f32_16x16x32_f16(a_lo, bh[c], acc[c], 0, 0, 0);
            acc[c] = __builtin_amdgcn_mfma_f32_16x16x32_f16(a_hi, bl[c], acc[c], 0, 0, 0);
        }
#pragma unroll
        for (int c = 0; c < 4; c++) { bh[c] = bnh[c]; bl[c] = bnl[c]; }
    }

    __syncthreads();   // all waves done reading buffer

    // --- fill pass 2: features 288..415 (RBF pairs i=17..24), col = c2-272 ---
    {
#pragma unroll
        for (int i = 17; i < 25; i++) {
            int c2 = 2 * (fj8 + 8 * i);
            int p  = c2 >> 4;
            int r  = c2 & 15;
            float D = dle[p];
            float mu0 = 2.0f + (float)r * (20.0f / 15.0f);
            float mu1 = 2.0f + (float)(r + 1) * (20.0f / 15.0f);
            float t0 = (D - mu0) * 0.8f;
            float t1 = (D - mu1) * 0.8f;
            float g0 = __builtin_amdgcn_exp2f(-(t0 * t0) * LOG2E);
            float g1 = __builtin_amdgcn_exp2f(-(t1 * t1) * LOG2E);
            float h0 = (float)(_Float16)g0, h1 = (float)(_Float16)g1;
            int col = c2 - 272;
            *(unsigned*)&fah[col] = pack2h(g0, g1);
            *(unsigned*)&fal[col] = pack2h(g0 - h0, g1 - h1);
        }
    }
    __syncthreads();

    // pass 2: k-tiles 9..12 (guard prefetch at kk==12)
#pragma unroll 1
    for (int kk = 9; kk < KT; kk++) {
        half8 a_hi = *(const half8*)(pah + (kk - 9) * 32);
        half8 a_lo = *(const half8*)(pal + (kk - 9) * 32);
        if (kk < KT - 1) {
#pragma unroll
            for (int c = 0; c < 4; c++) {
                int idx = ((kk + 1) * 8 + h * 4 + c) * 64 + lane;
                bnh[c] = Wfh[idx];
                bnl[c] = Wfl[idx];
            }
        }
#pragma unroll
        for (int c = 0; c < 4; c++) {
            acc[c] = __builtin_amdgcn_mfma_f32_16x16x32_f16(a_hi, bh[c], acc[c], 0, 0, 0);
            acc[c] = __builtin_amdgcn_mfma_f32_16x16x32_f16(a_lo, bh[c], acc[c], 0, 0, 0);
            acc[c] = __builtin_amdgcn_mfma_f32_16x16x32_f16(a_hi, bl[c], acc[c], 0, 0, 0);
        }
#pragma unroll
        for (int c = 0; c < 4; c++) { bh[c] = bnh[c]; bl[c] = bnl[c]; }
    }

    // --- LayerNorm epilogue: per edge, features split across wave pairs ---
    // D[row = quad*4 + r][col = m]; edge_local = strip + quad*4 + r.
    int elb = strip + quad * 4;
    float sarr[4];
#pragma unroll
    for (int r = 0; r < 4; r++) {
        float s = acc[0][r] + acc[1][r] + acc[2][r] + acc[3][r];
        for (int msk = 1; msk <= 8; msk <<= 1) s += __shfl_xor(s, msk);
        sarr[r] = s;                       // this wave's 64-feature partial
    }
    if (m == 0) {
#pragma unroll
        for (int r = 0; r < 4; r++) redS[h][elb + r] = sarr[r];
    }
    __syncthreads();
    float mu[4];
#pragma unroll
    for (int r = 0; r < 4; r++) mu[r] = (redS[0][elb + r] + redS[1][elb + r]) * (1.0f / 128.0f);
    __syncthreads();
    float dvv[4][4];
#pragma unroll
    for (int r = 0; r < 4; r++) {
        float v = 0.f;
#pragma unroll
        for (int c = 0; c < 4; c++) { dvv[c][r] = acc[c][r] - mu[r]; v += dvv[c][r] * dvv[c][r]; }
        for (int msk = 1; msk <= 8; msk <<= 1) v += __shfl_xor(v, msk);
        if (m == 0) redS[h][elb + r] = v;
    }
    __syncthreads();
#pragma unroll
    for (int r = 0; r < 4; r++) {
        float var  = (redS[0][elb + r] + redS[1][elb + r]) * (1.0f / 128.0f);
        float rstd = rsqrtf(var + 1e-5f);
        int e = e0 + elb + r;
        float* orow = out + (size_t)e * 128;
#pragma unroll
        for (int c = 0; c < 4; c++) {
            int n = (h * 4 + c) * 16 + m;
            orow[n] = dvv[c][r] * rstd * gamma[n] + beta[n];
        }
    }
}

// ---------------------------------------------------------------------------
extern "C" void kernel_launch(void* const* d_in, const int* in_sizes, int n_in,
                              void* d_out, int out_size, void* d_ws, size_t ws_size,
                              hipStream_t stream) {
    const float* X      = (const float*)d_in[0];
    const float* mask   = (const float*)d_in[1];
    const int*   resi   = (const int*)  d_in[2];
    const float* W_pos  = (const float*)d_in[3];
    const float* b_pos  = (const float*)d_in[4];
    const float* W_edge = (const float*)d_in[5];
    const float* gamma  = (const float*)d_in[6];
    const float* beta   = (const float*)d_in[7];
    float* out = (float*)d_out;

    float* atoms = (float*)d_ws;                                     // 491520 B
    int*   E_idx = (int*)((char*)d_ws + (size_t)NRES * 15 * 4);      // 983040 B
    half8* Wfh   = (half8*)((char*)d_ws + 1474560);                  // 106496 B
    half8* Wfl   = (half8*)((char*)d_ws + 1581056);                  // 106496 B
    float* caTx  = (float*)((char*)d_ws + 1687552);                  //  32768 B
    float* caTy  = (float*)((char*)d_ws + 1720320);                  //  32768 B
    float* caTz  = (float*)((char*)d_ws + 1753088);                  //  32768 B

    atoms_kernel<<<(NRES + 255) / 256, 256, 0, stream>>>(X, atoms, caTx, caTy, caTz);
    wprep_kernel<<<(KT * 8 * 64 + 255) / 256, 256, 0, stream>>>(W_edge, Wfh, Wfl);
    topk_kernel<<<NRES / 4, 256, 0, stream>>>(caTx, caTy, caTz, mask, E_idx);
    edge_kernel<<<NEDGE / ME, 256, 0, stream>>>(atoms, E_idx, resi,
                                                W_pos, b_pos, Wfh, Wfl, gamma, beta, out);
}

// Round 6
// 291.796 us; speedup vs baseline: 1.8514x; 1.0991x over previous
//
#include <hip/hip_runtime.h>
#include <hip/hip_bf16.h>
#include <math.h>

// Problem constants (fixed by setup_inputs: B=4, L=2048)
#define BB      4
#define LL      2048
#define KNB     30
#define NRES    (BB*LL)          // 8192
#define NEDGE   (NRES*KNB)       // 245760
#define EDGE_IN 416              // 16 pos + 25*16 RBF = 13 * 32
#define KT      13               // K-tiles of 32
#define ME      64               // edges per block in edge kernel
#define AST3    168              // A-tile row stride in fp16 for 5-tile buffer (336 B, 16B-aligned)
#define FINF    3.4e38f
#define LOG2E   1.44269504088896340736f

typedef __attribute__((ext_vector_type(8))) _Float16 half8;
typedef __attribute__((ext_vector_type(4))) float floatx4;

__device__ __constant__ int d_PA[25] = {0,1,2,3,4,0,0,0,0,1,1,1,4,4,3,1,2,3,4,2,3,4,2,3,2};
__device__ __constant__ int d_PB[25] = {0,1,2,3,4,1,2,3,4,2,3,4,2,3,2,0,0,0,0,1,1,1,4,4,3};

__device__ __forceinline__ unsigned short f2h_bits(float x) {
    _Float16 h = (_Float16)x;
    union { _Float16 h; unsigned short u; } v; v.h = h;
    return v.u;
}
__device__ __forceinline__ unsigned pack2h(float a, float b) {
    return (unsigned)f2h_bits(a) | ((unsigned)f2h_bits(b) << 16);
}

// ---------------------------------------------------------------------------
// Kernel 1: per-residue atom construction.  atoms[r][5][3] = [Ca,N,C,O,Cb].
// Also emits the Ca SoA transpose (caTx/y/z) for coalesced topk loads.
// ---------------------------------------------------------------------------
__global__ __launch_bounds__(256) void atoms_kernel(const float* __restrict__ X,
                                                    float* __restrict__ atoms,
                                                    float* __restrict__ caTx,
                                                    float* __restrict__ caTy,
                                                    float* __restrict__ caTz) {
    int r = blockIdx.x * blockDim.x + threadIdx.x;
    if (r >= NRES) return;
    const float* xr = X + (size_t)r * 12;
    float Nx = xr[0],  Ny = xr[1],  Nz = xr[2];
    float Ax = xr[3],  Ay = xr[4],  Az = xr[5];   // Ca
    float Cx = xr[6],  Cy = xr[7],  Cz = xr[8];
    float Ox = xr[9],  Oy = xr[10], Oz = xr[11];
    float bx = Ax - Nx, by = Ay - Ny, bz = Az - Nz;
    float cx = Cx - Ax, cy = Cy - Ay, cz = Cz - Az;
    float ax = by * cz - bz * cy;
    float ay = bz * cx - bx * cz;
    float az = bx * cy - by * cx;
    float Cbx = -0.58273431f * ax + 0.56802827f * bx - 0.54067466f * cx + Ax;
    float Cby = -0.58273431f * ay + 0.56802827f * by - 0.54067466f * cy + Ay;
    float Cbz = -0.58273431f * az + 0.56802827f * bz - 0.54067466f * cz + Az;
    float* o = atoms + (size_t)r * 15;
    o[0]  = Ax;  o[1]  = Ay;  o[2]  = Az;
    o[3]  = Nx;  o[4]  = Ny;  o[5]  = Nz;
    o[6]  = Cx;  o[7]  = Cy;  o[8]  = Cz;
    o[9]  = Ox;  o[10] = Oy;  o[11] = Oz;
    o[12] = Cbx; o[13] = Cby; o[14] = Cbz;
    caTx[r] = Ax; caTy[r] = Ay; caTz[r] = Az;     // exact copies of X values
}

// ---------------------------------------------------------------------------
// Kernel 2: top-K — ONE WAVE PER RESIDUE, cached-head tournament, ZERO LDS.
// (unchanged from round 5 — kept byte-identical so the edge_kernel delta is
// attributable; topk becomes the top dispatch next round => counters)
// ---------------------------------------------------------------------------
__global__ __launch_bounds__(256, 6) void topk_kernel(const float* __restrict__ caTx,
                                                      const float* __restrict__ caTy,
                                                      const float* __restrict__ caTz,
                                                      const float* __restrict__ mask,
                                                      int* __restrict__ E_idx) {
#pragma clang fp contract(off)
    int t    = threadIdx.x;
    int wid  = t >> 6;
    int lane = t & 63;
    int bi   = blockIdx.x * 4 + wid;      // residue
    int b    = bi >> 11;
    int j0   = b << 11;

    float cx = caTx[bi], cy = caTy[bi], cz = caTz[bi];
    float mi = mask[bi];

    float aa[32];
    float lmax = 0.0f;
#pragma unroll
    for (int i = 0; i < 32; i++) {
        int j = j0 + i * 64 + lane;
        float dx = cx - caTx[j], dy = cy - caTy[j], dz = cz - caTz[j];
        float ssq = ((dx * dx + dy * dy) + dz * dz) + 1e-6f;
        float m2  = mask[j] * mi;
        float Dj  = m2 * sqrtf(ssq);
        aa[i] = Dj;
        lmax = fmaxf(lmax, Dj);
    }
    for (int off = 32; off; off >>= 1) lmax = fmaxf(lmax, __shfl_xor(lmax, off));

    // adjust in place (exact no-op when mask==1) and build sorted-4 cache
    float l0 = FINF, l1 = FINF, l2 = FINF, l3 = FINF;
    int   i0 = 0,    i1 = 0,    i2 = 0,    i3 = 0;     // slot; global j = (slot<<6)|lane
#pragma unroll
    for (int i = 0; i < 32; i++) {
        float m2 = mask[j0 + i * 64 + lane] * mi;
        float v  = aa[i] + (1.0f - m2) * lmax;
        aa[i] = v;
        bool c0 = v < l0, c1 = v < l1, c2 = v < l2, c3 = v < l3;
        l3 = c2 ? l2 : (c3 ? v : l3);  i3 = c2 ? i2 : (c3 ? i : i3);
        l2 = c1 ? l1 : (c2 ? v : l2);  i2 = c1 ? i1 : (c2 ? i : i2);
        l1 = c0 ? l0 : (c1 ? v : l1);  i1 = c0 ? i0 : (c1 ? i : i1);
        l0 = c0 ? v  : l0;             i0 = c0 ? i  : i0;
    }

    unsigned consumed = 0;
    int* outp = E_idx + (size_t)bi * KNB;
#pragma unroll 1
    for (int r = 0; r < KNB; r++) {
        float bv = l0;
        int   bj = (i0 << 6) | lane;
        for (int off = 1; off < 64; off <<= 1) {
            float ov = __shfl_xor(bv, off);
            int   oj = __shfl_xor(bj, off);
            if (ov < bv || (ov == bv && oj < bj)) { bv = ov; bj = oj; }
        }
        if (lane == 0) outp[r] = bj;
        bool mine = ((bj & 63) == lane);
        if (mine) {
            consumed |= 1u << ((unsigned)bj >> 6);   // mark own slot consumed
            l0 = l1; i0 = i1;
            l1 = l2; i1 = i2;
            l2 = l3; i2 = i3;
            l3 = FINF;
        }
        bool need = mine && (l0 == FINF) && (r < KNB - 1);
        if (need) {                                  // rare: lane won a 5th time
            l0 = FINF; l1 = FINF; l2 = FINF; l3 = FINF;
            i0 = 0; i1 = 0; i2 = 0; i3 = 0;
#pragma unroll
            for (int i = 0; i < 32; i++) {
                float v = (consumed & (1u << i)) ? FINF : aa[i];
                bool c0 = v < l0, c1 = v < l1, c2 = v < l2, c3 = v < l3;
                l3 = c2 ? l2 : (c3 ? v : l3);  i3 = c2 ? i2 : (c3 ? i : i3);
                l2 = c1 ? l1 : (c2 ? v : l2);  i2 = c1 ? i1 : (c2 ? i : i2);
                l1 = c0 ? l0 : (c1 ? v : l1);  i1 = c0 ? i0 : (c1 ? i : i1);
                l0 = c0 ? v  : l0;             i0 = c0 ? i  : i0;
            }
        }
    }
}

// ---------------------------------------------------------------------------
// Kernel 2.5: pre-swizzle W_edge (fp32 [416][128]) into SPLIT fp16 B-fragment
// order: Wh = fp16(W), Wl = fp16(W - Wh).  Layout [kk][nt][lane] of half8:
// element holds W[k = kk*32 + (lane>>4)*8 + j][n = nt*16 + (lane&15)].
// ---------------------------------------------------------------------------
__global__ __launch_bounds__(256) void wprep_kernel(const float* __restrict__ W_edge,
                                                    half8* __restrict__ Wfh,
                                                    half8* __restrict__ Wfl) {
    int t = blockIdx.x * blockDim.x + threadIdx.x;
    if (t >= KT * 8 * 64) return;
    int kk   = t >> 9;
    int rem  = t & 511;
    int nt   = rem >> 6;
    int lane = rem & 63;
    int n  = nt * 16 + (lane & 15);
    int kb = kk * 32 + (lane >> 4) * 8;
    half8 vh, vl;
#pragma unroll
    for (int j = 0; j < 8; j++) {
        float w = W_edge[(size_t)(kb + j) * 128 + n];
        _Float16 wh = (_Float16)w;
        vh[j] = wh;
        vl[j] = (_Float16)(w - (float)wh);
    }
    Wfh[t] = vh;
    Wfl[t] = vl;
}

// ---------------------------------------------------------------------------
// Kernel 3: edge featurization (SPLIT fp16 A-tile) + 3-term MFMA GEMM + LN.
// ME = 64 edges/block: each wave computes TWO 16-row strips against the SAME
// B fragments (acc[2][4], 24 MFMA/kk) — halves per-edge W L2 traffic (was
// 3.3 GB = ~20 TB/s L2) and per-edge K-loop overhead, doubles MFMA per load.
// Per-edge kk order and 3-term MFMA order unchanged => bit-identical output.
// 3-way K time-split over a 5-tile buffer; LDS ~51 KB -> 3 blocks/CU.
// ---------------------------------------------------------------------------
__global__ __launch_bounds__(256) void edge_kernel(const float* __restrict__ atoms,
                                                   const int* __restrict__ E_idx,
                                                   const int* __restrict__ resi,
                                                   const float* __restrict__ W_pos,
                                                   const float* __restrict__ b_pos,
                                                   const half8* __restrict__ Wfh,
                                                   const half8* __restrict__ Wfl,
                                                   const float* __restrict__ gamma,
                                                   const float* __restrict__ beta,
                                                   float* __restrict__ out) {
    __shared__ _Float16 Ah[ME * AST3];             // 21504 B
    __shared__ _Float16 Al[ME * AST3];             // 21504 B
    __shared__ float Dl[ME][26];                   //  6656 B
    __shared__ float redS[2][ME];                  //   512 B
    __shared__ int   s_gi[ME], s_gj[ME], s_d[ME];  //   768 B

    int t  = threadIdx.x;
    int e0 = blockIdx.x * ME;

    if (t < ME) {
        int e  = e0 + t;
        int gi = e / KNB;
        int k  = e - gi * KNB;
        int b  = gi >> 11;
        int j  = E_idx[(size_t)gi * KNB + k];
        s_gi[t] = gi;
        s_gj[t] = (b << 11) + j;
        int off = resi[gi] - resi[(b << 11) + j];
        int d = off + 32;
        s_d[t] = d < 0 ? 0 : (d > 64 ? 64 : d);
    }
    __syncthreads();

    for (int idx = t; idx < ME * 25; idx += 256) {
        int e = idx / 25, p = idx - e * 25;
        const float* Ar = atoms + (size_t)s_gi[e] * 15 + d_PA[p] * 3;
        const float* Br = atoms + (size_t)s_gj[e] * 15 + d_PB[p] * 3;
        float dx = Ar[0] - Br[0];
        float dy = Ar[1] - Br[1];
        float dz = Ar[2] - Br[2];
        Dl[e][p] = sqrtf(dx * dx + dy * dy + dz * dz + 1e-6f);
    }
    __syncthreads();

    int fe  = t >> 2;           // 0..63 (edge for fill)
    int fj4 = t & 3;
    const float* dle = Dl[fe];
    _Float16* fah = &Ah[fe * AST3];
    _Float16* fal = &Al[fe * AST3];

    // --- fill pass 0: features 0..159 (pos-emb + RBF pairs i=0..17) ---
    {
        {                          // pos-emb features c = fj4*4 .. +3
            int c = fj4 * 4;
            int dpos = s_d[fe];
            const float* wp = W_pos + dpos * 16 + c;
            float v[4];
#pragma unroll
            for (int q = 0; q < 4; q++) v[q] = wp[q] + b_pos[c + q];
            float h0 = (float)(_Float16)v[0], h1 = (float)(_Float16)v[1];
            float h2 = (float)(_Float16)v[2], h3 = (float)(_Float16)v[3];
            *(unsigned*)&fah[c + 0] = pack2h(v[0], v[1]);
            *(unsigned*)&fah[c + 2] = pack2h(v[2], v[3]);
            *(unsigned*)&fal[c + 0] = pack2h(v[0] - h0, v[1] - h1);
            *(unsigned*)&fal[c + 2] = pack2h(v[2] - h2, v[3] - h3);
        }
        // RBF pairs: c2 = 2*(fj4 + 4i), i = 0..17 -> buffer col 16+c2 (<=158)
#pragma unroll
        for (int i = 0; i < 18; i++) {
            int c2 = 2 * (fj4 + 4 * i);
            int p  = c2 >> 4;
            int r  = c2 & 15;
            float D = dle[p];
            float mu0 = 2.0f + (float)r * (20.0f / 15.0f);
            float mu1 = 2.0f + (float)(r + 1) * (20.0f / 15.0f);
            float t0 = (D - mu0) * 0.8f;
            float t1 = (D - mu1) * 0.8f;
            float g0 = __builtin_amdgcn_exp2f(-(t0 * t0) * LOG2E);
            float g1 = __builtin_amdgcn_exp2f(-(t1 * t1) * LOG2E);
            float h0 = (float)(_Float16)g0, h1 = (float)(_Float16)g1;
            *(unsigned*)&fah[16 + c2] = pack2h(g0, g1);
            *(unsigned*)&fal[16 + c2] = pack2h(g0 - h0, g1 - h1);
        }
    }
    __syncthreads();

    // --- MFMA GEMM: 64x416 x 416x128 -> fp32, split precision, 3-way K split ---
    int lane  = t & 63;
    int w     = t >> 6;
    int ms    = w & 1;             // edge strip pair: rows ms*32 .. ms*32+31
    int h     = w >> 1;            // feature half (0: n 0..63, 1: n 64..127)
    int m     = lane & 15;
    int quad  = lane >> 4;
    const _Float16* pah = &Ah[(ms * 32 + m) * AST3 + quad * 8];
    const _Float16* pal = &Al[(ms * 32 + m) * AST3 + quad * 8];

    floatx4 acc[2][4];
#pragma unroll
    for (int s = 0; s < 2; s++)
#pragma unroll
        for (int c = 0; c < 4; c++) acc[s][c] = (floatx4){0.f, 0.f, 0.f, 0.f};

    half8 bh[4], bl[4], bnh[4], bnl[4];
#pragma unroll
    for (int c = 0; c < 4; c++) {
        int idx = (h * 4 + c) * 64 + lane;
        bh[c] = Wfh[idx];
        bl[c] = Wfl[idx];
    }

    // pass 0: k-tiles 0..4 (prefetch kk+1 <= 5 always valid)
#pragma unroll 1
    for (int kk = 0; kk < 5; kk++) {
        half8 a_hi0 = *(const half8*)(pah + kk * 32);
        half8 a_lo0 = *(const half8*)(pal + kk * 32);
        half8 a_hi1 = *(const half8*)(pah + 16 * AST3 + kk * 32);
        half8 a_lo1 = *(const half8*)(pal + 16 * AST3 + kk * 32);
#pragma unroll
        for (int c = 0; c < 4; c++) {
            int idx = ((kk + 1) * 8 + h * 4 + c) * 64 + lane;
            bnh[c] = Wfh[idx];
            bnl[c] = Wfl[idx];
        }
#pragma unroll
        for (int c = 0; c < 4; c++) {
            acc[0][c] = __builtin_amdgcn_mfma_f32_16x16x32_f16(a_hi0, bh[c], acc[0][c], 0, 0, 0);
            acc[1][c] = __builtin_amdgcn_mfma_f32_16x16x32_f16(a_hi1, bh[c], acc[1][c], 0, 0, 0);
            acc[0][c] = __builtin_amdgcn_mfma_f32_16x16x32_f16(a_lo0, bh[c], acc[0][c], 0, 0, 0);
            acc[1][c] = __builtin_amdgcn_mfma_f32_16x16x32_f16(a_lo1, bh[c], acc[1][c], 0, 0, 0);
            acc[0][c] = __builtin_amdgcn_mfma_f32_16x16x32_f16(a_hi0, bl[c], acc[0][c], 0, 0, 0);
            acc[1][c] = __builtin_amdgcn_mfma_f32_16x16x32_f16(a_hi1, bl[c], acc[1][c], 0, 0, 0);
        }
#pragma unroll
        for (int c = 0; c < 4; c++) { bh[c] = bnh[c]; bl[c] = bnl[c]; }
    }

    __syncthreads();   // all waves done reading buffer

    // --- fill pass 1: features 160..287 (RBF pairs i=18..33), col = c2-144 ---
    {
#pragma unroll
        for (int i = 18; i < 34; i++) {
            int c2 = 2 * (fj4 + 4 * i);
            int p  = c2 >> 4;
            int r  = c2 & 15;
            float D = dle[p];
            float mu0 = 2.0f + (float)r * (20.0f / 15.0f);
            float mu1 = 2.0f + (float)(r + 1) * (20.0f / 15.0f);
            float t0 = (D - mu0) * 0.8f;
            float t1 = (D - mu1) * 0.8f;
            float g0 = __builtin_amdgcn_exp2f(-(t0 * t0) * LOG2E);
            float g1 = __builtin_amdgcn_exp2f(-(t1 * t1) * LOG2E);
            float h0 = (float)(_Float16)g0, h1 = (float)(_Float16)g1;
            int col = c2 - 144;
            *(unsigned*)&fah[col] = pack2h(g0, g1);
            *(unsigned*)&fal[col] = pack2h(g0 - h0, g1 - h1);
        }
    }
    __syncthreads();

    // pass 1: k-tiles 5..8 (prefetch kk+1 <= 9 always valid)
#pragma unroll 1
    for (int kk = 5; kk < 9; kk++) {
        half8 a_hi0 = *(const half8*)(pah + (kk - 5) * 32);
        half8 a_lo0 = *(const half8*)(pal + (kk - 5) * 32);
        half8 a_hi1 = *(const half8*)(pah + 16 * AST3 + (kk - 5) * 32);
        half8 a_lo1 = *(const half8*)(pal + 16 * AST3 + (kk - 5) * 32);
#pragma unroll
        for (int c = 0; c < 4; c++) {
            int idx = ((kk + 1) * 8 + h * 4 + c) * 64 + lane;
            bnh[c] = Wfh[idx];
            bnl[c] = Wfl[idx];
        }
#pragma unroll
        for (int c = 0; c < 4; c++) {
            acc[0][c] = __builtin_amdgcn_mfma_f32_16x16x32_f16(a_hi0, bh[c], acc[0][c], 0, 0, 0);
            acc[1][c] = __builtin_amdgcn_mfma_f32_16x16x32_f16(a_hi1, bh[c], acc[1][c], 0, 0, 0);
            acc[0][c] = __builtin_amdgcn_mfma_f32_16x16x32_f16(a_lo0, bh[c], acc[0][c], 0, 0, 0);
            acc[1][c] = __builtin_amdgcn_mfma_f32_16x16x32_f16(a_lo1, bh[c], acc[1][c], 0, 0, 0);
            acc[0][c] = __builtin_amdgcn_mfma_f32_16x16x32_f16(a_hi0, bl[c], acc[0][c], 0, 0, 0);
            acc[1][c] = __builtin_amdgcn_mfma_f32_16x16x32_f16(a_hi1, bl[c], acc[1][c], 0, 0, 0);
        }
#pragma unroll
        for (int c = 0; c < 4; c++) { bh[c] = bnh[c]; bl[c] = bnl[c]; }
    }

    __syncthreads();   // all waves done reading buffer

    // --- fill pass 2: features 288..415 (RBF pairs i=34..49), col = c2-272 ---
    {
#pragma unroll
        for (int i = 34; i < 50; i++) {
            int c2 = 2 * (fj4 + 4 * i);
            int p  = c2 >> 4;
            int r  = c2 & 15;
            float D = dle[p];
            float mu0 = 2.0f + (float)r * (20.0f / 15.0f);
            float mu1 = 2.0f + (float)(r + 1) * (20.0f / 15.0f);
            float t0 = (D - mu0) * 0.8f;
            float t1 = (D - mu1) * 0.8f;
            float g0 = __builtin_amdgcn_exp2f(-(t0 * t0) * LOG2E);
            float g1 = __builtin_amdgcn_exp2f(-(t1 * t1) * LOG2E);
            float h0 = (float)(_Float16)g0, h1 = (float)(_Float16)g1;
            int col = c2 - 272;
            *(unsigned*)&fah[col] = pack2h(g0, g1);
            *(unsigned*)&fal[col] = pack2h(g0 - h0, g1 - h1);
        }
    }
    __syncthreads();

    // pass 2: k-tiles 9..12 (guard prefetch at kk==12)
#pragma unroll 1
    for (int kk = 9; kk < KT; kk++) {
        half8 a_hi0 = *(const half8*)(pah + (kk - 9) * 32);
        half8 a_lo0 = *(const half8*)(pal + (kk - 9) * 32);
        half8 a_hi1 = *(const half8*)(pah + 16 * AST3 + (kk - 9) * 32);
        half8 a_lo1 = *(const half8*)(pal + 16 * AST3 + (kk - 9) * 32);
        if (kk < KT - 1) {
#pragma unroll
            for (int c = 0; c < 4; c++) {
                int idx = ((kk + 1) * 8 + h * 4 + c) * 64 + lane;
                bnh[c] = Wfh[idx];
                bnl[c] = Wfl[idx];
            }
        }
#pragma unroll
        for (int c = 0; c < 4; c++) {
            acc[0][c] = __builtin_amdgcn_mfma_f32_16x16x32_f16(a_hi0, bh[c], acc[0][c], 0, 0, 0);
            acc[1][c] = __builtin_amdgcn_mfma_f32_16x16x32_f16(a_hi1, bh[c], acc[1][c], 0, 0, 0);
            acc[0][c] = __builtin_amdgcn_mfma_f32_16x16x32_f16(a_lo0, bh[c], acc[0][c], 0, 0, 0);
            acc[1][c] = __builtin_amdgcn_mfma_f32_16x16x32_f16(a_lo1, bh[c], acc[1][c], 0, 0, 0);
            acc[0][c] = __builtin_amdgcn_mfma_f32_16x16x32_f16(a_hi0, bl[c], acc[0][c], 0, 0, 0);
            acc[1][c] = __builtin_amdgcn_mfma_f32_16x16x32_f16(a_hi1, bl[c], acc[1][c], 0, 0, 0);
        }
#pragma unroll
        for (int c = 0; c < 4; c++) { bh[c] = bnh[c]; bl[c] = bnl[c]; }
    }

    // --- LayerNorm epilogue: per edge, features split across wave pairs ---
    // D[row = quad*4 + r][col = m] per strip; edge_local = ms*32 + s*16 + quad*4 + r.
#pragma unroll
    for (int s = 0; s < 2; s++) {
        int elb = ms * 32 + s * 16 + quad * 4;
        float sarr[4];
#pragma unroll
        for (int r = 0; r < 4; r++) {
            float sm = acc[s][0][r] + acc[s][1][r] + acc[s][2][r] + acc[s][3][r];
            for (int msk = 1; msk <= 8; msk <<= 1) sm += __shfl_xor(sm, msk);
            sarr[r] = sm;
        }
        if (m == 0) {
#pragma unroll
            for (int r = 0; r < 4; r++) redS[h][elb + r] = sarr[r];
        }
        __syncthreads();
        float mu[4];
#pragma unroll
        for (int r = 0; r < 4; r++) mu[r] = (redS[0][elb + r] + redS[1][elb + r]) * (1.0f / 128.0f);
        __syncthreads();
        float dvv[4][4];
#pragma unroll
        for (int r = 0; r < 4; r++) {
            float v = 0.f;
#pragma unroll
            for (int c = 0; c < 4; c++) { dvv[c][r] = acc[s][c][r] - mu[r]; v += dvv[c][r] * dvv[c][r]; }
            for (int msk = 1; msk <= 8; msk <<= 1) v += __shfl_xor(v, msk);
            if (m == 0) redS[h][elb + r] = v;
        }
        __syncthreads();
#pragma unroll
        for (int r = 0; r < 4; r++) {
            float var  = (redS[0][elb + r] + redS[1][elb + r]) * (1.0f / 128.0f);
            float rstd = rsqrtf(var + 1e-5f);
            int e = e0 + elb + r;
            float* orow = out + (size_t)e * 128;
#pragma unroll
            for (int c = 0; c < 4; c++) {
                int n = (h * 4 + c) * 16 + m;
                orow[n] = dvv[c][r] * rstd * gamma[n] + beta[n];
            }
        }
        if (s == 0) __syncthreads();   // redS reused by strip 1
    }
}

// ---------------------------------------------------------------------------
extern "C" void kernel_launch(void* const* d_in, const int* in_sizes, int n_in,
                              void* d_out, int out_size, void* d_ws, size_t ws_size,
                              hipStream_t stream) {
    const float* X      = (const float*)d_in[0];
    const float* mask   = (const float*)d_in[1];
    const int*   resi   = (const int*)  d_in[2];
    const float* W_pos  = (const float*)d_in[3];
    const float* b_pos  = (const float*)d_in[4];
    const float* W_edge = (const float*)d_in[5];
    const float* gamma  = (const float*)d_in[6];
    const float* beta   = (const float*)d_in[7];
    float* out = (float*)d_out;

    float* atoms = (float*)d_ws;                                     // 491520 B
    int*   E_idx = (int*)((char*)d_ws + (size_t)NRES * 15 * 4);      // 983040 B
    half8* Wfh   = (half8*)((char*)d_ws + 1474560);                  // 106496 B
    half8* Wfl   = (half8*)((char*)d_ws + 1581056);                  // 106496 B
    float* caTx  = (float*)((char*)d_ws + 1687552);                  //  32768 B
    float* caTy  = (float*)((char*)d_ws + 1720320);                  //  32768 B
    float* caTz  = (float*)((char*)d_ws + 1753088);                  //  32768 B

    atoms_kernel<<<(NRES + 255) / 256, 256, 0, stream>>>(X, atoms, caTx, caTy, caTz);
    wprep_kernel<<<(KT * 8 * 64 + 255) / 256, 256, 0, stream>>>(W_edge, Wfh, Wfl);
    topk_kernel<<<NRES / 4, 256, 0, stream>>>(caTx, caTy, caTz, mask, E_idx);
    edge_kernel<<<NEDGE / ME, 256, 0, stream>>>(atoms, E_idx, resi,
                                                W_pos, b_pos, Wfh, Wfl, gamma, beta, out);
}